// Round 3
// baseline (674.033 us; speedup 1.0000x reference)
//
#include <hip/hip_runtime.h>
#include <cstdint>

// DynamicConvAttention: B=4, S=2048, D=1024, NH=16 (groups), K=3
// Inputs/outputs are FLOAT32 (per reference); internal GEMM compute bf16 MFMA.
//
// Workspace (65 MB):
//   wT    [0,   8 MB)  bf16 transposed WqT,WkT,WvT,WoT (1M u16 each)
//   qkvb  [8,   8+12KB) f32 concat bias [bq | 0 | bv]
//   Q     [9,  25 MB)  bf16 [8192][1024]   (reused as attn per batch)
//   K     [25, 41 MB)  bf16                (reused as combined)
//   V     [41, 57 MB)  bf16                (reused as conv buffer)
//   P     [57, 65 MB)  bf16 [2048][2048] per-batch scores/probs
// d_out (f32, 32 MB) doubles as scratch:
//   xb = d_out[0:16MB)   bf16 copy of x   (dead after conv)
//   vt = d_out[16:32MB)  bf16 V^T [B][1024][2048] (dead after PV)
// Final GEMM overwrites all of d_out with f32 results.

#define DEV __device__ __forceinline__

typedef unsigned short u16;
typedef __attribute__((ext_vector_type(8))) short bf16x8;
typedef __attribute__((ext_vector_type(4))) float f32x4;

static const int Sn = 2048, Dn = 1024;

DEV float bf2f(u16 u) { union { unsigned int i; float f; } w; w.i = ((unsigned int)u) << 16; return w.f; }
DEV u16 f2bf(float f) {
  union { float f; unsigned int i; } w; w.f = f;
  unsigned int x = w.i;
  return (u16)((x + 0x7FFFu + ((x >> 16) & 1u)) >> 16);
}

DEV float block_allreduce_sum(float v, float* red, int tid) {
  #pragma unroll
  for (int o = 32; o > 0; o >>= 1) v += __shfl_down(v, o, 64);
  __syncthreads();
  if ((tid & 63) == 0) red[tid >> 6] = v;
  __syncthreads();
  return red[0] + red[1] + red[2] + red[3];
}

DEV float block_allreduce_max(float v, float* red, int tid) {
  #pragma unroll
  for (int o = 32; o > 0; o >>= 1) v = fmaxf(v, __shfl_down(v, o, 64));
  __syncthreads();
  if ((tid & 63) == 0) red[tid >> 6] = v;
  __syncthreads();
  return fmaxf(fmaxf(red[0], red[1]), fmaxf(red[2], red[3]));
}

// ---------------- f32 -> bf16 elementwise convert ----------------
__global__ __launch_bounds__(256)
void cvt_f32_bf16(const float* __restrict__ s, u16* __restrict__ d, int n) {
  int i = (blockIdx.x * 256 + threadIdx.x) * 4;
  if (i >= n) return;
  float4 v = *(const float4*)&s[i];
  ushort4 o;
  o.x = f2bf(v.x); o.y = f2bf(v.y); o.z = f2bf(v.z); o.w = f2bf(v.w);
  *(ushort4*)&d[i] = o;
}

// ---------------- transpose f32 src -> bf16 dst (64x64 tiles) ----------------
__global__ __launch_bounds__(256)
void transpose_cvt(const float* __restrict__ src, u16* __restrict__ dst,
                   int src_ld, int dst_ld) {
  __shared__ u16 sm[64][68];
  int i0 = blockIdx.y << 6, j0 = blockIdx.x << 6;
  int tid = threadIdx.x, tx = tid & 15, r0 = tid >> 4;
  #pragma unroll
  for (int rr = r0; rr < 64; rr += 16) {
    float4 v = *(const float4*)&src[(long)(i0 + rr) * src_ld + j0 + tx * 4];
    sm[rr][tx*4+0] = f2bf(v.x); sm[rr][tx*4+1] = f2bf(v.y);
    sm[rr][tx*4+2] = f2bf(v.z); sm[rr][tx*4+3] = f2bf(v.w);
  }
  __syncthreads();
  #pragma unroll
  for (int cc = r0; cc < 64; cc += 16) {
    ushort4 o;
    o.x = sm[tx*4+0][cc]; o.y = sm[tx*4+1][cc];
    o.z = sm[tx*4+2][cc]; o.w = sm[tx*4+3][cc];
    *(ushort4*)&dst[(long)(j0 + cc) * dst_ld + i0 + tx * 4] = o;
  }
}

// ---------------- transpose bf16 -> bf16 (64x64 tiles, z-batched) ----------------
__global__ __launch_bounds__(256)
void transpose_u16(const u16* __restrict__ src, u16* __restrict__ dst,
                   int src_ld, int dst_ld, long sbs, long dbs) {
  __shared__ u16 sm[64][68];
  const u16* s = src + (long)blockIdx.z * sbs;
  u16* d = dst + (long)blockIdx.z * dbs;
  int i0 = blockIdx.y << 6, j0 = blockIdx.x << 6;
  int tid = threadIdx.x, tx = tid & 15, r0 = tid >> 4;
  #pragma unroll
  for (int rr = r0; rr < 64; rr += 16) {
    ushort4 v = *(const ushort4*)&s[(long)(i0 + rr) * src_ld + j0 + tx * 4];
    sm[rr][tx*4+0] = v.x; sm[rr][tx*4+1] = v.y; sm[rr][tx*4+2] = v.z; sm[rr][tx*4+3] = v.w;
  }
  __syncthreads();
  #pragma unroll
  for (int cc = r0; cc < 64; cc += 16) {
    ushort4 o;
    o.x = sm[tx*4+0][cc]; o.y = sm[tx*4+1][cc];
    o.z = sm[tx*4+2][cc]; o.w = sm[tx*4+3][cc];
    *(ushort4*)&d[(long)(j0 + cc) * dst_ld + i0 + tx * 4] = o;
  }
}

// ---------------- qkv bias concat (f32) ----------------
__global__ void concat_bias(const float* __restrict__ bq, const float* __restrict__ bv,
                            float* __restrict__ qb) {
  int j = blockIdx.x * 256 + threadIdx.x;
  if (j >= 3072) return;
  float v = 0.0f;
  if (j < 1024) v = bq[j];
  else if (j >= 2048) v = bv[j - 2048];
  qb[j] = v;
}

// ---------------- NT GEMM: C = scale*(A Bt) + bias[n] (+res); bf16 in, CT out ----
// 128x128 tile, BK=32, 256 threads (4 waves, 2x2 of 64x64), mfma 16x16x32 bf16.
template<typename CT>
__global__ __launch_bounds__(256, 2)
void gemm_nt(const u16* __restrict__ A, long Abs, int lda,
             const u16* __restrict__ B, long Bbs, int ldb,
             CT* __restrict__ C, long Cbs, int ldc,
             int K, float scale,
             const float* __restrict__ bias, int bias_bs,
             const float* __restrict__ res, long Rbs, int ldr) {
  __shared__ u16 sA[128 * 40];
  __shared__ u16 sB[128 * 40];
  int tid = threadIdx.x;
  int lane = tid & 63, wv = tid >> 6;
  int quad = lane >> 4, lm = lane & 15;
  int wr = wv >> 1, wc = wv & 1;
  long m0 = (long)blockIdx.x * 128, n0 = (long)blockIdx.y * 128;
  A += (long)blockIdx.z * Abs;
  B += (long)blockIdx.z * Bbs;
  C += (long)blockIdx.z * Cbs;
  if (res) res += (long)blockIdx.z * Rbs;

  f32x4 acc[4][4] = {};

  const int c8 = (tid & 3) * 8;
  const int rbase = tid >> 2;

  for (int k0 = 0; k0 < K; k0 += 32) {
    #pragma unroll
    for (int i = 0; i < 2; i++) {
      int row = i * 64 + rbase;
      uint4 va = *(const uint4*)&A[(m0 + row) * (long)lda + k0 + c8];
      *(uint4*)&sA[row * 40 + c8] = va;
      uint4 vb = *(const uint4*)&B[(n0 + row) * (long)ldb + k0 + c8];
      *(uint4*)&sB[row * 40 + c8] = vb;
    }
    __syncthreads();
    bf16x8 af[4], bfr[4];
    #pragma unroll
    for (int mi = 0; mi < 4; mi++)
      af[mi] = *(const bf16x8*)&sA[(wr * 64 + mi * 16 + lm) * 40 + quad * 8];
    #pragma unroll
    for (int ni = 0; ni < 4; ni++)
      bfr[ni] = *(const bf16x8*)&sB[(wc * 64 + ni * 16 + lm) * 40 + quad * 8];
    #pragma unroll
    for (int mi = 0; mi < 4; mi++)
      #pragma unroll
      for (int ni = 0; ni < 4; ni++)
        acc[mi][ni] = __builtin_amdgcn_mfma_f32_16x16x32_bf16(af[mi], bfr[ni], acc[mi][ni], 0, 0, 0);
    __syncthreads();
  }

  // C/D layout: col=lane&15, row=quad*4+reg (m89/m91 verified)
  #pragma unroll
  for (int mi = 0; mi < 4; mi++) {
    #pragma unroll
    for (int ni = 0; ni < 4; ni++) {
      int col = (int)n0 + wc * 64 + ni * 16 + lm;
      float bv = bias ? bias[(long)blockIdx.z * bias_bs + col] : 0.0f;
      #pragma unroll
      for (int r = 0; r < 4; r++) {
        long rowg = m0 + wr * 64 + mi * 16 + quad * 4 + r;
        float v = acc[mi][ni][r] * scale + bv;
        if (res) v += res[rowg * (long)ldr + col];
        if constexpr (sizeof(CT) == 2) C[rowg * (long)ldc + col] = f2bf(v);
        else                           C[rowg * (long)ldc + col] = v;
      }
    }
  }
}

// ---------------- grouped conv1d (K=3, pad=1), 64 ch/group ----------------
// x: bf16 [B][S][D]; w: f32 [1024][64][3]; out bf16. grid (S/128, NH, B), 256 thr.
__global__ __launch_bounds__(256)
void conv_grouped(const u16* __restrict__ x, const float* __restrict__ w,
                  const float* __restrict__ cbias, u16* __restrict__ out) {
  __shared__ u16 sx[130][64];
  __shared__ float sw[3][64][64];  // [tap][i][oc]
  int s0 = blockIdx.x * 128;
  int g = blockIdx.y;
  int b = blockIdx.z;
  int tid = threadIdx.x;

  for (int idx = tid; idx < 64 * 64 * 3; idx += 256) {
    int oc = idx / 192; int rem = idx - oc * 192; int i = rem / 3; int t = rem - i * 3;
    sw[t][i][oc] = w[(g * 64 + oc) * 192 + i * 3 + t];
  }
  for (int idx = tid; idx < 130 * 16; idx += 256) {
    int r = idx >> 4; int c4 = (idx & 15) * 4;
    int s = s0 - 1 + r;
    ushort4 v;
    if (s >= 0 && s < Sn) v = *(const ushort4*)&x[(long)b * Sn * Dn + (long)s * Dn + g * 64 + c4];
    else { v.x = 0; v.y = 0; v.z = 0; v.w = 0; }
    *(ushort4*)&sx[r][c4] = v;
  }
  __syncthreads();

  int oc = tid & 63, sb = tid >> 6;
  float acc[32];
  float bv = cbias[g * 64 + oc];
  #pragma unroll
  for (int j = 0; j < 32; j++) acc[j] = bv;

  for (int t = 0; t < 3; t++) {
    for (int i4 = 0; i4 < 16; i4++) {
      float w0 = sw[t][i4 * 4 + 0][oc];
      float w1 = sw[t][i4 * 4 + 1][oc];
      float w2 = sw[t][i4 * 4 + 2][oc];
      float w3 = sw[t][i4 * 4 + 3][oc];
      #pragma unroll
      for (int j = 0; j < 32; j++) {
        int srow = sb + 4 * j + t;
        ushort4 xv = *(const ushort4*)&sx[srow][i4 * 4];
        acc[j] += bf2f(xv.x) * w0 + bf2f(xv.y) * w1 + bf2f(xv.z) * w2 + bf2f(xv.w) * w3;
      }
    }
  }
  #pragma unroll
  for (int j = 0; j < 32; j++) {
    int s = s0 + sb + 4 * j;
    out[(long)b * Sn * Dn + (long)s * Dn + g * 64 + oc] = f2bf(acc[j]);
  }
}

// ---------------- layernorm (torch-style, ddof=1, eps on std); optional add ----
// a,b2,out bf16; gamma,beta f32. Safe in-place (reads precede barriers).
__global__ __launch_bounds__(256)
void ln_kernel(const u16* __restrict__ a, const u16* __restrict__ b2,
               const float* __restrict__ gamma, const float* __restrict__ beta,
               u16* __restrict__ out) {
  __shared__ float red[4];
  long row = blockIdx.x;
  int tid = threadIdx.x;
  long base = row * Dn + tid * 4;
  ushort4 av = *(const ushort4*)&a[base];
  float v0 = bf2f(av.x), v1 = bf2f(av.y), v2 = bf2f(av.z), v3 = bf2f(av.w);
  if (b2) {
    ushort4 bv4 = *(const ushort4*)&b2[base];
    v0 += bf2f(bv4.x); v1 += bf2f(bv4.y); v2 += bf2f(bv4.z); v3 += bf2f(bv4.w);
  }
  float s = block_allreduce_sum(v0 + v1 + v2 + v3, red, tid);
  float mean = s * (1.0f / 1024.0f);
  float d0 = v0 - mean, d1 = v1 - mean, d2 = v2 - mean, d3 = v3 - mean;
  float sq = block_allreduce_sum(d0 * d0 + d1 * d1 + d2 * d2 + d3 * d3, red, tid);
  float inv = 1.0f / (sqrtf(sq * (1.0f / 1023.0f)) + 1e-6f);
  float4 gv = *(const float4*)&gamma[tid * 4];
  float4 bev = *(const float4*)&beta[tid * 4];
  ushort4 o;
  o.x = f2bf(gv.x * d0 * inv + bev.x);
  o.y = f2bf(gv.y * d1 * inv + bev.y);
  o.z = f2bf(gv.z * d2 * inv + bev.z);
  o.w = f2bf(gv.w * d3 * inv + bev.w);
  *(ushort4*)&out[base] = o;
}

// ---------------- softmax over bf16 rows of 2048, in place ----------------
__global__ __launch_bounds__(256)
void softmax_bf16(u16* __restrict__ scores) {
  __shared__ float red[4];
  long row = blockIdx.x;
  u16* p = scores + row * 2048;
  int tid = threadIdx.x;
  ushort4 a = *(const ushort4*)&p[tid * 8];
  ushort4 b = *(const ushort4*)&p[tid * 8 + 4];
  float f0 = bf2f(a.x), f1 = bf2f(a.y), f2 = bf2f(a.z), f3 = bf2f(a.w);
  float f4 = bf2f(b.x), f5 = bf2f(b.y), f6 = bf2f(b.z), f7 = bf2f(b.w);
  float m = fmaxf(fmaxf(fmaxf(f0, f1), fmaxf(f2, f3)),
                  fmaxf(fmaxf(f4, f5), fmaxf(f6, f7)));
  m = block_allreduce_max(m, red, tid);
  float e0 = __expf(f0 - m), e1 = __expf(f1 - m), e2 = __expf(f2 - m), e3 = __expf(f3 - m);
  float e4 = __expf(f4 - m), e5 = __expf(f5 - m), e6 = __expf(f6 - m), e7 = __expf(f7 - m);
  float s = block_allreduce_sum(e0 + e1 + e2 + e3 + e4 + e5 + e6 + e7, red, tid);
  float inv = 1.0f / s;
  ushort4 o1, o2;
  o1.x = f2bf(e0 * inv); o1.y = f2bf(e1 * inv); o1.z = f2bf(e2 * inv); o1.w = f2bf(e3 * inv);
  o2.x = f2bf(e4 * inv); o2.y = f2bf(e5 * inv); o2.z = f2bf(e6 * inv); o2.w = f2bf(e7 * inv);
  *(ushort4*)&p[tid * 8] = o1;
  *(ushort4*)&p[tid * 8 + 4] = o2;
}

// ---------------- workspace layout (bytes); total 65 MB ----------------
static const size_t OFF_WT   = 0;               // 8 MB (4x 1M u16)
static const size_t OFF_QKVB = 8ull << 20;      // 12 KB f32
static const size_t OFF_Q    = 9ull << 20;      // 16 MB bf16 [8192][1024]
static const size_t OFF_K    = 25ull << 20;     // 16 MB
static const size_t OFF_V    = 41ull << 20;     // 16 MB (reused as conv buffer)
static const size_t OFF_P    = 57ull << 20;     // 8 MB bf16 [2048][2048] per batch

extern "C" void kernel_launch(void* const* d_in, const int* in_sizes, int n_in,
                              void* d_out, int out_size, void* d_ws, size_t ws_size,
                              hipStream_t stream) {
  const float* x     = (const float*)d_in[0];
  const float* Wq    = (const float*)d_in[1];
  const float* bq    = (const float*)d_in[2];
  const float* Wk    = (const float*)d_in[3];
  const float* Wv    = (const float*)d_in[4];
  const float* bv    = (const float*)d_in[5];
  const float* cw    = (const float*)d_in[6];
  const float* cb    = (const float*)d_in[7];
  const float* gamma = (const float*)d_in[8];
  const float* beta  = (const float*)d_in[9];
  const float* Wo    = (const float*)d_in[10];
  const float* bo    = (const float*)d_in[11];
  float* out = (float*)d_out;
  char* ws = (char*)d_ws;

  u16*   wT   = (u16*)(ws + OFF_WT);
  float* qkvb = (float*)(ws + OFF_QKVB);
  u16*   Qb   = (u16*)(ws + OFF_Q);
  u16*   Kb   = (u16*)(ws + OFF_K);
  u16*   Vb   = (u16*)(ws + OFF_V);
  u16*   P    = (u16*)(ws + OFF_P);
  u16*   xb   = (u16*)d_out;               // d_out[0:16MB): bf16 x (dead after conv)
  u16*   vt   = (u16*)d_out + 8388608;     // d_out[16:32MB): V^T (dead after PV)
  u16*   conv = Vb;                        // V region reused after V->vt
  u16*   attn = Qb;                        // Q_b overwritten after scores_b
  u16*   combined = Kb;                    // K dead after all scores

  dim3 tb(256);

  // 1. weight transpose+convert -> wT (WqT|WkT|WvT|WoT), 1M u16 each
  transpose_cvt<<<dim3(16, 16), tb, 0, stream>>>(Wq, wT + 0u * 1048576u, 1024, 1024);
  transpose_cvt<<<dim3(16, 16), tb, 0, stream>>>(Wk, wT + 1u * 1048576u, 1024, 1024);
  transpose_cvt<<<dim3(16, 16), tb, 0, stream>>>(Wv, wT + 2u * 1048576u, 1024, 1024);
  transpose_cvt<<<dim3(16, 16), tb, 0, stream>>>(Wo, wT + 3u * 1048576u, 1024, 1024);
  // 2. bias concat [bq | 0 | bv] (f32)
  concat_bias<<<dim3(12), tb, 0, stream>>>(bq, bv, qkvb);
  // 3. x -> bf16 (into d_out scratch)
  cvt_f32_bf16<<<dim3(8192), tb, 0, stream>>>(x, xb, 8388608);
  // 4. QKV: z in {Q,K,V}; planes contiguous (stride 8M u16)
  gemm_nt<u16><<<dim3(64, 8, 3), tb, 0, stream>>>(
      xb, 0, 1024, wT, 1048576, 1024, Qb, 8388608, 1024,
      1024, 1.0f, qkvb, 1024, nullptr, 0, 0);
  // 5. V^T per batch: [2048,1024] -> [1024,2048] into d_out scratch
  transpose_u16<<<dim3(16, 32, 4), tb, 0, stream>>>(
      Vb, vt, 1024, 2048, (long)Sn * Dn, (long)Dn * Sn);
  // 6. grouped conv (reads xb) -> conv (over old V region)
  conv_grouped<<<dim3(16, 16, 4), tb, 0, stream>>>(xb, cw, cb, conv);
  // 7. LN(conv) in place
  ln_kernel<<<dim3(8192), tb, 0, stream>>>(conv, nullptr, gamma, beta, conv);
  // 8. attention per batch (P is 8 MB, reused)
  for (int b = 0; b < 4; b++) {
    long qoff = (long)b * Sn * Dn;
    gemm_nt<u16><<<dim3(16, 16, 1), tb, 0, stream>>>(
        Qb + qoff, 0, 1024, Kb + qoff, 0, 1024,
        P, 0, 2048, 1024, 0.03125f, nullptr, 0, nullptr, 0, 0);
    softmax_bf16<<<dim3(2048), tb, 0, stream>>>(P);
    gemm_nt<u16><<<dim3(16, 8, 1), tb, 0, stream>>>(
        P, 0, 2048, vt + qoff, 0, 2048,
        attn + qoff, 0, 1024, 2048, 1.0f, nullptr, 0, nullptr, 0, 0);
  }
  // 9. combined = LN(conv + attn) -> K region
  ln_kernel<<<dim3(8192), tb, 0, stream>>>(conv, attn, gamma, beta, combined);
  // 10. out = combined @ Wo + bo + x  (f32 output, f32 residual)
  gemm_nt<float><<<dim3(64, 8, 1), tb, 0, stream>>>(
      combined, 0, 1024, wT + 3u * 1048576u, 0, 1024,
      out, 0, 1024, 1024, 1.0f, bo, 0, x, 0, 1024);
}

// Round 4
// 444.772 us; speedup vs baseline: 1.5155x; 1.5155x over previous
//
#include <hip/hip_runtime.h>
#include <cstdint>

// DynamicConvAttention: B=4, S=2048, D=1024, NH=16 (groups), K=3
// f32 I/O, bf16 MFMA internal.
//
// ws (57.5 MB):
//   wT      [0, 8 MB)        bf16 WqT,WkT,WvT,WoT (1M u16 each)
//   qkvb    [8 MB, +12 KB)   f32 concat bias
//   wt_conv [8 MB+64KB, +384KB) bf16 conv weights [1024][192], k=t*64+i
//   Q       [9, 25 MB)  bf16 [8192][1024]  (attn written over consumed chunks)
//   K       [25, 41 MB) bf16               (combined after scores)
//   V       [41, 57 MB) bf16               (conv buffer after V->vt)
// d_out (33.5 MB f32) as scratch:
//   xb = d_out[0:16.8MB)  bf16 x           (dead after conv)
//   P2 = same region      bf16 [2][2048][2048] per-chunk scores (after conv)
//   vt = d_out[+8M u16]   bf16 V^T [4][1024][2048] (dead after PV)
// Final GEMM overwrites d_out with f32.

#define DEV __device__ __forceinline__

typedef unsigned short u16;
typedef __attribute__((ext_vector_type(8))) short bf16x8;
typedef __attribute__((ext_vector_type(4))) float f32x4;

static const int Sn = 2048, Dn = 1024;

DEV float bf2f(u16 u) { union { unsigned int i; float f; } w; w.i = ((unsigned int)u) << 16; return w.f; }
DEV u16 f2bf(float f) {
  union { float f; unsigned int i; } w; w.f = f;
  unsigned int x = w.i;
  return (u16)((x + 0x7FFFu + ((x >> 16) & 1u)) >> 16);
}

// async global->LDS, 16 B per lane; lds dst must be wave-uniform (lane*16 auto)
DEV void gload_lds16(const u16* gsrc, u16* lds_dst) {
  __builtin_amdgcn_global_load_lds(
      (const __attribute__((address_space(1))) void*)gsrc,
      (__attribute__((address_space(3))) void*)lds_dst,
      16, 0, 0);
}

DEV float block_allreduce_sum(float v, float* red, int tid) {
  #pragma unroll
  for (int o = 32; o > 0; o >>= 1) v += __shfl_down(v, o, 64);
  __syncthreads();
  if ((tid & 63) == 0) red[tid >> 6] = v;
  __syncthreads();
  return red[0] + red[1] + red[2] + red[3];
}

DEV float block_allreduce_max(float v, float* red, int tid) {
  #pragma unroll
  for (int o = 32; o > 0; o >>= 1) v = fmaxf(v, __shfl_down(v, o, 64));
  __syncthreads();
  if ((tid & 63) == 0) red[tid >> 6] = v;
  __syncthreads();
  return fmaxf(fmaxf(red[0], red[1]), fmaxf(red[2], red[3]));
}

// ---------------- f32 -> bf16 elementwise ----------------
__global__ __launch_bounds__(256)
void cvt_f32_bf16(const float* __restrict__ s, u16* __restrict__ d, int n) {
  int i = (blockIdx.x * 256 + threadIdx.x) * 4;
  if (i >= n) return;
  float4 v = *(const float4*)&s[i];
  ushort4 o;
  o.x = f2bf(v.x); o.y = f2bf(v.y); o.z = f2bf(v.z); o.w = f2bf(v.w);
  *(ushort4*)&d[i] = o;
}

// ---------------- transpose f32 -> bf16 (64x64 tiles) ----------------
__global__ __launch_bounds__(256)
void transpose_cvt(const float* __restrict__ src, u16* __restrict__ dst,
                   int src_ld, int dst_ld) {
  __shared__ u16 sm[64][68];
  int i0 = blockIdx.y << 6, j0 = blockIdx.x << 6;
  int tid = threadIdx.x, tx = tid & 15, r0 = tid >> 4;
  #pragma unroll
  for (int rr = r0; rr < 64; rr += 16) {
    float4 v = *(const float4*)&src[(long)(i0 + rr) * src_ld + j0 + tx * 4];
    sm[rr][tx*4+0] = f2bf(v.x); sm[rr][tx*4+1] = f2bf(v.y);
    sm[rr][tx*4+2] = f2bf(v.z); sm[rr][tx*4+3] = f2bf(v.w);
  }
  __syncthreads();
  #pragma unroll
  for (int cc = r0; cc < 64; cc += 16) {
    ushort4 o;
    o.x = sm[tx*4+0][cc]; o.y = sm[tx*4+1][cc];
    o.z = sm[tx*4+2][cc]; o.w = sm[tx*4+3][cc];
    *(ushort4*)&dst[(long)(j0 + cc) * dst_ld + i0 + tx * 4] = o;
  }
}

// ---------------- transpose bf16 -> bf16 (64x64 tiles, z-batched) ----------------
__global__ __launch_bounds__(256)
void transpose_u16(const u16* __restrict__ src, u16* __restrict__ dst,
                   int src_ld, int dst_ld, long sbs, long dbs) {
  __shared__ u16 sm[64][68];
  const u16* s = src + (long)blockIdx.z * sbs;
  u16* d = dst + (long)blockIdx.z * dbs;
  int i0 = blockIdx.y << 6, j0 = blockIdx.x << 6;
  int tid = threadIdx.x, tx = tid & 15, r0 = tid >> 4;
  #pragma unroll
  for (int rr = r0; rr < 64; rr += 16) {
    ushort4 v = *(const ushort4*)&s[(long)(i0 + rr) * src_ld + j0 + tx * 4];
    sm[rr][tx*4+0] = v.x; sm[rr][tx*4+1] = v.y; sm[rr][tx*4+2] = v.z; sm[rr][tx*4+3] = v.w;
  }
  __syncthreads();
  #pragma unroll
  for (int cc = r0; cc < 64; cc += 16) {
    ushort4 o;
    o.x = sm[tx*4+0][cc]; o.y = sm[tx*4+1][cc];
    o.z = sm[tx*4+2][cc]; o.w = sm[tx*4+3][cc];
    *(ushort4*)&d[(long)(j0 + cc) * dst_ld + i0 + tx * 4] = o;
  }
}

// ---------------- qkv bias concat (f32) ----------------
__global__ void concat_bias(const float* __restrict__ bq, const float* __restrict__ bv,
                            float* __restrict__ qb) {
  int j = blockIdx.x * 256 + threadIdx.x;
  if (j >= 3072) return;
  float v = 0.0f;
  if (j < 1024) v = bq[j];
  else if (j >= 2048) v = bv[j - 2048];
  qb[j] = v;
}

// ---------------- conv weight prep: [1024][64][3] f32 -> [1024][192] bf16, k=t*64+i ----
__global__ void conv_w_prep(const float* __restrict__ w, u16* __restrict__ wt) {
  int oc = blockIdx.x;
  int k = threadIdx.x;             // 0..191
  int t = k >> 6, i = k & 63;
  wt[oc * 192 + k] = f2bf(w[oc * 192 + i * 3 + t]);
}

// ---------------- NT GEMM with global_load_lds staging (m97 structure) ----------
// 128x128 tile, BK=32, 256 threads (4 waves 2x2), mfma 16x16x32 bf16.
// LDS tiles UNPADDED 128x32 row-major (required by global_load_lds lane order).
template<typename CT>
__global__ __launch_bounds__(256, 2)
void gemm_nt(const u16* __restrict__ A, long Abs, int lda,
             const u16* __restrict__ B, long Bbs, int ldb,
             CT* __restrict__ C, long Cbs, int ldc,
             int K, float scale,
             const float* __restrict__ bias, int bias_bs,
             const float* __restrict__ res, long Rbs, int ldr) {
  __shared__ u16 sA[128 * 32];
  __shared__ u16 sB[128 * 32];
  int tid = threadIdx.x;
  int lane = tid & 63, wv = tid >> 6;
  int quad = lane >> 4, lm = lane & 15;
  int wr = wv >> 1, wc = wv & 1;
  long m0 = (long)blockIdx.x * 128, n0 = (long)blockIdx.y * 128;
  A += (long)blockIdx.z * Abs;
  B += (long)blockIdx.z * Bbs;
  C += (long)blockIdx.z * Cbs;
  if (res) res += (long)blockIdx.z * Rbs;

  f32x4 acc[4][4] = {};

  // staging: wave wv covers rows [wv*16, wv*16+16) (+64 for second call);
  // lane covers row wv*16 + (lane>>2), 16B chunk (lane&3)*8 elems -> LDS base + lane*16B
  int srow = wv * 16 + (lane >> 2);
  int sch = (lane & 3) * 8;
  const u16* Ap = A + (m0 + srow) * (long)lda + sch;
  const u16* Bp = B + (n0 + srow) * (long)ldb + sch;
  u16* lA = &sA[wv * 16 * 32];
  u16* lB = &sB[wv * 16 * 32];

  for (int k0 = 0; k0 < K; k0 += 32) {
    gload_lds16(Ap + k0, lA);
    gload_lds16(Ap + 64 * (long)lda + k0, lA + 64 * 32);
    gload_lds16(Bp + k0, lB);
    gload_lds16(Bp + 64 * (long)ldb + k0, lB + 64 * 32);
    __syncthreads();   // drains vmcnt: LDS tiles visible
    bf16x8 af[4], bfr[4];
    #pragma unroll
    for (int mi = 0; mi < 4; mi++)
      af[mi] = *(const bf16x8*)&sA[(wr * 64 + mi * 16 + lm) * 32 + quad * 8];
    #pragma unroll
    for (int ni = 0; ni < 4; ni++)
      bfr[ni] = *(const bf16x8*)&sB[(wc * 64 + ni * 16 + lm) * 32 + quad * 8];
    #pragma unroll
    for (int mi = 0; mi < 4; mi++)
      #pragma unroll
      for (int ni = 0; ni < 4; ni++)
        acc[mi][ni] = __builtin_amdgcn_mfma_f32_16x16x32_bf16(af[mi], bfr[ni], acc[mi][ni], 0, 0, 0);
    __syncthreads();   // frag reads done before next iteration overwrites
  }

  // C/D layout: col=lane&15, row=quad*4+reg (m89/m91 verified)
  #pragma unroll
  for (int mi = 0; mi < 4; mi++) {
    #pragma unroll
    for (int ni = 0; ni < 4; ni++) {
      int col = (int)n0 + wc * 64 + ni * 16 + lm;
      float bv = bias ? bias[(long)blockIdx.z * bias_bs + col] : 0.0f;
      #pragma unroll
      for (int r = 0; r < 4; r++) {
        long rowg = m0 + wr * 64 + mi * 16 + quad * 4 + r;
        float v = acc[mi][ni][r] * scale + bv;
        if (res) v += res[rowg * (long)ldr + col];
        if constexpr (sizeof(CT) == 2) C[rowg * (long)ldc + col] = f2bf(v);
        else                           C[rowg * (long)ldc + col] = v;
      }
    }
  }
}

// ---------------- grouped conv1d via MFMA ----------------
// Per (s-tile 128, g, b): out[s,oc] = bias[oc] + sum_k A[s,k]*W[oc,k],
// k = t*64+i, A[s,k] = x[s+t-1, g*64+i] (im2col folded into sx row offset).
// M=128/block (4 waves x 32 rows), N=64, K=192 (6 MFMA ksteps). No k-loop barriers.
__global__ __launch_bounds__(256)
void conv_mfma(const u16* __restrict__ xb, const u16* __restrict__ wt,
               const float* __restrict__ cb, u16* __restrict__ out) {
  __shared__ u16 sx[130][72];   // rows s0-1 .. s0+128; pad 64->72 breaks bank aliasing
  int s0 = blockIdx.x * 128;
  int g = blockIdx.y;
  int b = blockIdx.z;
  int tid = threadIdx.x, lane = tid & 63, wv = tid >> 6;
  int quad = lane >> 4, lm = lane & 15;

  for (int idx = tid; idx < 130 * 16; idx += 256) {
    int r = idx >> 4, c4 = (idx & 15) * 4;
    int s = s0 - 1 + r;
    ushort4 v;
    if (s >= 0 && s < Sn) v = *(const ushort4*)&xb[((long)b * Sn + s) * Dn + g * 64 + c4];
    else { v.x = 0; v.y = 0; v.z = 0; v.w = 0; }
    *(ushort4*)&sx[r][c4] = v;
  }
  __syncthreads();

  f32x4 acc[2][4] = {};
  const u16* wg = wt + (long)g * 64 * 192;
  #pragma unroll
  for (int ks = 0; ks < 6; ks++) {
    int t = ks >> 1;
    int i0 = (ks & 1) * 32 + quad * 8;
    bf16x8 a0 = *(const bf16x8*)&sx[wv * 32 + lm + t][i0];
    bf16x8 a1 = *(const bf16x8*)&sx[wv * 32 + 16 + lm + t][i0];
    #pragma unroll
    for (int nf = 0; nf < 4; nf++) {
      bf16x8 bf = *(const bf16x8*)&wg[(nf * 16 + lm) * 192 + ks * 32 + quad * 8];
      acc[0][nf] = __builtin_amdgcn_mfma_f32_16x16x32_bf16(a0, bf, acc[0][nf], 0, 0, 0);
      acc[1][nf] = __builtin_amdgcn_mfma_f32_16x16x32_bf16(a1, bf, acc[1][nf], 0, 0, 0);
    }
  }
  #pragma unroll
  for (int mi = 0; mi < 2; mi++) {
    #pragma unroll
    for (int nf = 0; nf < 4; nf++) {
      int col = g * 64 + nf * 16 + lm;
      float bias = cb[col];
      #pragma unroll
      for (int r = 0; r < 4; r++) {
        int row = wv * 32 + mi * 16 + quad * 4 + r;
        out[((long)b * Sn + s0 + row) * Dn + col] = f2bf(acc[mi][nf][r] + bias);
      }
    }
  }
}

// ---------------- layernorm (ddof=1, eps on std); optional add; in-place safe ----
__global__ __launch_bounds__(256)
void ln_kernel(const u16* __restrict__ a, const u16* __restrict__ b2,
               const float* __restrict__ gamma, const float* __restrict__ beta,
               u16* __restrict__ out) {
  __shared__ float red[4];
  long row = blockIdx.x;
  int tid = threadIdx.x;
  long base = row * Dn + tid * 4;
  ushort4 av = *(const ushort4*)&a[base];
  float v0 = bf2f(av.x), v1 = bf2f(av.y), v2 = bf2f(av.z), v3 = bf2f(av.w);
  if (b2) {
    ushort4 bv4 = *(const ushort4*)&b2[base];
    v0 += bf2f(bv4.x); v1 += bf2f(bv4.y); v2 += bf2f(bv4.z); v3 += bf2f(bv4.w);
  }
  float s = block_allreduce_sum(v0 + v1 + v2 + v3, red, tid);
  float mean = s * (1.0f / 1024.0f);
  float d0 = v0 - mean, d1 = v1 - mean, d2 = v2 - mean, d3 = v3 - mean;
  float sq = block_allreduce_sum(d0 * d0 + d1 * d1 + d2 * d2 + d3 * d3, red, tid);
  float inv = 1.0f / (sqrtf(sq * (1.0f / 1023.0f)) + 1e-6f);
  float4 gv = *(const float4*)&gamma[tid * 4];
  float4 bev = *(const float4*)&beta[tid * 4];
  ushort4 o;
  o.x = f2bf(gv.x * d0 * inv + bev.x);
  o.y = f2bf(gv.y * d1 * inv + bev.y);
  o.z = f2bf(gv.z * d2 * inv + bev.z);
  o.w = f2bf(gv.w * d3 * inv + bev.w);
  *(ushort4*)&out[base] = o;
}

// ---------------- softmax over bf16 rows of 2048, in place ----------------
__global__ __launch_bounds__(256)
void softmax_bf16(u16* __restrict__ scores) {
  __shared__ float red[4];
  long row = blockIdx.x;
  u16* p = scores + row * 2048;
  int tid = threadIdx.x;
  ushort4 a = *(const ushort4*)&p[tid * 8];
  ushort4 b = *(const ushort4*)&p[tid * 8 + 4];
  float f0 = bf2f(a.x), f1 = bf2f(a.y), f2 = bf2f(a.z), f3 = bf2f(a.w);
  float f4 = bf2f(b.x), f5 = bf2f(b.y), f6 = bf2f(b.z), f7 = bf2f(b.w);
  float m = fmaxf(fmaxf(fmaxf(f0, f1), fmaxf(f2, f3)),
                  fmaxf(fmaxf(f4, f5), fmaxf(f6, f7)));
  m = block_allreduce_max(m, red, tid);
  float e0 = __expf(f0 - m), e1 = __expf(f1 - m), e2 = __expf(f2 - m), e3 = __expf(f3 - m);
  float e4 = __expf(f4 - m), e5 = __expf(f5 - m), e6 = __expf(f6 - m), e7 = __expf(f7 - m);
  float s = block_allreduce_sum(e0 + e1 + e2 + e3 + e4 + e5 + e6 + e7, red, tid);
  float inv = 1.0f / s;
  ushort4 o1, o2;
  o1.x = f2bf(e0 * inv); o1.y = f2bf(e1 * inv); o1.z = f2bf(e2 * inv); o1.w = f2bf(e3 * inv);
  o2.x = f2bf(e4 * inv); o2.y = f2bf(e5 * inv); o2.z = f2bf(e6 * inv); o2.w = f2bf(e7 * inv);
  *(ushort4*)&p[tid * 8] = o1;
  *(ushort4*)&p[tid * 8 + 4] = o2;
}

// ---------------- workspace layout ----------------
static const size_t OFF_WT    = 0;                        // 8 MB
static const size_t OFF_QKVB  = 8ull << 20;               // 12 KB f32
static const size_t OFF_WCONV = (8ull << 20) + (64 << 10); // 384 KB bf16
static const size_t OFF_Q     = 9ull << 20;               // 16 MB
static const size_t OFF_K     = 25ull << 20;              // 16 MB
static const size_t OFF_V     = 41ull << 20;              // 16 MB (conv buffer later)

extern "C" void kernel_launch(void* const* d_in, const int* in_sizes, int n_in,
                              void* d_out, int out_size, void* d_ws, size_t ws_size,
                              hipStream_t stream) {
  const float* x     = (const float*)d_in[0];
  const float* Wq    = (const float*)d_in[1];
  const float* bq    = (const float*)d_in[2];
  const float* Wk    = (const float*)d_in[3];
  const float* Wv    = (const float*)d_in[4];
  const float* bv    = (const float*)d_in[5];
  const float* cw    = (const float*)d_in[6];
  const float* cb    = (const float*)d_in[7];
  const float* gamma = (const float*)d_in[8];
  const float* beta  = (const float*)d_in[9];
  const float* Wo    = (const float*)d_in[10];
  const float* bo    = (const float*)d_in[11];
  float* out = (float*)d_out;
  char* ws = (char*)d_ws;

  u16*   wT    = (u16*)(ws + OFF_WT);
  float* qkvb  = (float*)(ws + OFF_QKVB);
  u16*   wconv = (u16*)(ws + OFF_WCONV);
  u16*   Qb    = (u16*)(ws + OFF_Q);
  u16*   Kb    = (u16*)(ws + OFF_K);
  u16*   Vb    = (u16*)(ws + OFF_V);
  u16*   xb    = (u16*)d_out;               // [0, 16.8MB): bf16 x, dead after conv
  u16*   P2    = (u16*)d_out;               // same region: [2][2048][2048] scores
  u16*   vt    = (u16*)d_out + 8388608;     // [16.8, 33.5MB): V^T, dead after PV
  u16*   conv  = Vb;
  u16*   attn  = Qb;                        // chunk c only overwrites consumed Q rows
  u16*   combined = Kb;

  dim3 tb(256);

  // prep
  transpose_cvt<<<dim3(16, 16), tb, 0, stream>>>(Wq, wT + 0u * 1048576u, 1024, 1024);
  transpose_cvt<<<dim3(16, 16), tb, 0, stream>>>(Wk, wT + 1u * 1048576u, 1024, 1024);
  transpose_cvt<<<dim3(16, 16), tb, 0, stream>>>(Wv, wT + 2u * 1048576u, 1024, 1024);
  transpose_cvt<<<dim3(16, 16), tb, 0, stream>>>(Wo, wT + 3u * 1048576u, 1024, 1024);
  concat_bias<<<dim3(12), tb, 0, stream>>>(bq, bv, qkvb);
  conv_w_prep<<<dim3(1024), dim3(192), 0, stream>>>(cw, wconv);
  cvt_f32_bf16<<<dim3(8192), tb, 0, stream>>>(x, xb, 8388608);

  // QKV (z = Q,K,V planes)
  gemm_nt<u16><<<dim3(64, 8, 3), tb, 0, stream>>>(
      xb, 0, 1024, wT, 1048576, 1024, Qb, 8388608, 1024,
      1024, 1.0f, qkvb, 1024, nullptr, 0, 0);
  // V^T per batch -> vt
  transpose_u16<<<dim3(16, 32, 4), tb, 0, stream>>>(
      Vb, vt, 1024, 2048, (long)Sn * Dn, (long)Dn * Sn);
  // conv (MFMA) -> conv region; then LN in place. xb dead after this.
  conv_mfma<<<dim3(16, 16, 4), tb, 0, stream>>>(xb, wconv, cb, conv);
  ln_kernel<<<dim3(8192), tb, 0, stream>>>(conv, nullptr, gamma, beta, conv);

  // attention in 2 chunks of 2 batches (P2 lives in the dead-xb region of d_out)
  for (int c = 0; c < 2; c++) {
    long off = (long)c * 2 * Sn * Dn;
    gemm_nt<u16><<<dim3(16, 16, 2), tb, 0, stream>>>(
        Qb + off, (long)Sn * Dn, 1024, Kb + off, (long)Sn * Dn, 1024,
        P2, (long)Sn * Sn, 2048, 1024, 0.03125f, nullptr, 0, nullptr, 0, 0);
    softmax_bf16<<<dim3(4096), tb, 0, stream>>>(P2);
    gemm_nt<u16><<<dim3(16, 8, 2), tb, 0, stream>>>(
        P2, (long)Sn * Sn, 2048, vt + off, (long)Dn * Sn, 2048,
        attn + off, (long)Sn * Dn, 1024, 2048, 1.0f, nullptr, 0, nullptr, 0, 0);
  }

  // combined = LN(conv + attn); out = combined @ Wo + bo + x
  ln_kernel<<<dim3(8192), tb, 0, stream>>>(conv, attn, gamma, beta, combined);
  gemm_nt<float><<<dim3(64, 8, 1), tb, 0, stream>>>(
      combined, 0, 1024, wT + 3u * 1048576u, 0, 1024,
      out, 0, 1024, 1024, 1.0f, bo, 0, x, 0, 1024);
}

// Round 6
// 383.358 us; speedup vs baseline: 1.7582x; 1.1602x over previous
//
#include <hip/hip_runtime.h>
#include <cstdint>

// DynamicConvAttention: B=4, S=2048, D=1024, NH=16 (groups), K=3
// f32 I/O, bf16 MFMA internal.
//
// ws (73 MB primary path):
//   wT      [0, 8 MB)        bf16 WqT,WkT,WvT,WoT (1M u16 each)
//   qkvb    [8 MB, +12 KB)   f32 concat bias
//   wt_conv [8 MB+64KB, +384KB) bf16 conv weights [1024][192], k=t*64+i
//   Q       [9, 25 MB)  bf16 [8192][1024]  (attn overwrites after scores)
//   K       [25, 41 MB) bf16               (combined after scores)
//   V       [41, 57 MB) bf16               (conv buffer after V->vt)
//   Pw      [57, 73 MB) bf16 P batches 2,3 (4096 rows) — primary path only
// d_out (33.5 MB f32) as scratch:
//   xb = d_out[0:16.78MB)  bf16 x          (dead after conv)
//   Pd = same region       bf16 P batches 0,1 (4096 rows)
//   vt = d_out[+8388608 u16] bf16 V^T [4][1024][2048] (dead after PV)
// NOTE: P total rows = B*S = 8192 (4096 per region). Round-5 bug was
// softmax<<<16384>>>/rowsplit=8192, which softmaxed the vt region too.

#define DEV __device__ __forceinline__

typedef unsigned short u16;
typedef __attribute__((ext_vector_type(8))) short bf16x8;
typedef __attribute__((ext_vector_type(4))) float f32x4;

static const int Sn = 2048, Dn = 1024;

DEV float bf2f(u16 u) { union { unsigned int i; float f; } w; w.i = ((unsigned int)u) << 16; return w.f; }
DEV u16 f2bf(float f) {
  union { float f; unsigned int i; } w; w.f = f;
  unsigned int x = w.i;
  return (u16)((x + 0x7FFFu + ((x >> 16) & 1u)) >> 16);
}

DEV void gload_lds16(const u16* gsrc, u16* lds_dst) {
  __builtin_amdgcn_global_load_lds(
      (const __attribute__((address_space(1))) void*)gsrc,
      (__attribute__((address_space(3))) void*)lds_dst,
      16, 0, 0);
}

DEV float block_allreduce_sum(float v, float* red, int tid) {
  #pragma unroll
  for (int o = 32; o > 0; o >>= 1) v += __shfl_down(v, o, 64);
  __syncthreads();
  if ((tid & 63) == 0) red[tid >> 6] = v;
  __syncthreads();
  return red[0] + red[1] + red[2] + red[3];
}

DEV float block_allreduce_max(float v, float* red, int tid) {
  #pragma unroll
  for (int o = 32; o > 0; o >>= 1) v = fmaxf(v, __shfl_down(v, o, 64));
  __syncthreads();
  if ((tid & 63) == 0) red[tid >> 6] = v;
  __syncthreads();
  return fmaxf(fmaxf(red[0], red[1]), fmaxf(red[2], red[3]));
}

// ---------------- f32 -> bf16 elementwise ----------------
__global__ __launch_bounds__(256)
void cvt_f32_bf16(const float* __restrict__ s, u16* __restrict__ d, int n) {
  int i = (blockIdx.x * 256 + threadIdx.x) * 4;
  if (i >= n) return;
  float4 v = *(const float4*)&s[i];
  ushort4 o;
  o.x = f2bf(v.x); o.y = f2bf(v.y); o.z = f2bf(v.z); o.w = f2bf(v.w);
  *(ushort4*)&d[i] = o;
}

// ---------------- 4-way transpose f32 -> bf16 (64x64 tiles, z picks weight) ----
__global__ __launch_bounds__(256)
void transpose_cvt4(const float* __restrict__ w0, const float* __restrict__ w1,
                    const float* __restrict__ w2, const float* __restrict__ w3,
                    u16* __restrict__ dst_base) {
  __shared__ u16 sm[64][68];
  int z = blockIdx.z;
  const float* src = (z == 0) ? w0 : (z == 1) ? w1 : (z == 2) ? w2 : w3;
  u16* dst = dst_base + (size_t)z * 1048576u;
  int i0 = blockIdx.y << 6, j0 = blockIdx.x << 6;
  int tid = threadIdx.x, tx = tid & 15, r0 = tid >> 4;
  #pragma unroll
  for (int rr = r0; rr < 64; rr += 16) {
    float4 v = *(const float4*)&src[(long)(i0 + rr) * 1024 + j0 + tx * 4];
    sm[rr][tx*4+0] = f2bf(v.x); sm[rr][tx*4+1] = f2bf(v.y);
    sm[rr][tx*4+2] = f2bf(v.z); sm[rr][tx*4+3] = f2bf(v.w);
  }
  __syncthreads();
  #pragma unroll
  for (int cc = r0; cc < 64; cc += 16) {
    ushort4 o;
    o.x = sm[tx*4+0][cc]; o.y = sm[tx*4+1][cc];
    o.z = sm[tx*4+2][cc]; o.w = sm[tx*4+3][cc];
    *(ushort4*)&dst[(long)(j0 + cc) * 1024 + i0 + tx * 4] = o;
  }
}

// ---------------- transpose bf16 -> bf16 (64x64 tiles, z-batched) ----------------
__global__ __launch_bounds__(256)
void transpose_u16(const u16* __restrict__ src, u16* __restrict__ dst,
                   int src_ld, int dst_ld, long sbs, long dbs) {
  __shared__ u16 sm[64][68];
  const u16* s = src + (long)blockIdx.z * sbs;
  u16* d = dst + (long)blockIdx.z * dbs;
  int i0 = blockIdx.y << 6, j0 = blockIdx.x << 6;
  int tid = threadIdx.x, tx = tid & 15, r0 = tid >> 4;
  #pragma unroll
  for (int rr = r0; rr < 64; rr += 16) {
    ushort4 v = *(const ushort4*)&s[(long)(i0 + rr) * src_ld + j0 + tx * 4];
    sm[rr][tx*4+0] = v.x; sm[rr][tx*4+1] = v.y; sm[rr][tx*4+2] = v.z; sm[rr][tx*4+3] = v.w;
  }
  __syncthreads();
  #pragma unroll
  for (int cc = r0; cc < 64; cc += 16) {
    ushort4 o;
    o.x = sm[tx*4+0][cc]; o.y = sm[tx*4+1][cc];
    o.z = sm[tx*4+2][cc]; o.w = sm[tx*4+3][cc];
    *(ushort4*)&d[(long)(j0 + cc) * dst_ld + i0 + tx * 4] = o;
  }
}

// ---------------- qkv bias concat (f32) ----------------
__global__ void concat_bias(const float* __restrict__ bq, const float* __restrict__ bv,
                            float* __restrict__ qb) {
  int j = blockIdx.x * 256 + threadIdx.x;
  if (j >= 3072) return;
  float v = 0.0f;
  if (j < 1024) v = bq[j];
  else if (j >= 2048) v = bv[j - 2048];
  qb[j] = v;
}

// ---------------- conv weight prep: [1024][64][3] f32 -> [1024][192] bf16 ----
__global__ void conv_w_prep(const float* __restrict__ w, u16* __restrict__ wt) {
  int oc = blockIdx.x;
  int k = threadIdx.x;             // 0..191
  int t = k >> 6, i = k & 63;
  wt[oc * 192 + k] = f2bf(w[oc * 192 + i * 3 + t]);
}

// ---------------- NT GEMM with global_load_lds staging (m97 structure) ----------
// 128x128 tile, BK=32, 256 threads (4 waves 2x2), mfma 16x16x32 bf16.
// A2/C2 + zsplit: blocks with z >= zsplit use the secondary base pointer.
template<typename CT>
__global__ __launch_bounds__(256, 2)
void gemm_nt(const u16* __restrict__ A, const u16* __restrict__ A2, long Abs, int lda,
             const u16* __restrict__ B, long Bbs, int ldb,
             CT* __restrict__ C, CT* __restrict__ C2, long Cbs, int ldc,
             int zsplit, int K, float scale,
             const float* __restrict__ bias, int bias_bs,
             const float* __restrict__ res, long Rbs, int ldr) {
  __shared__ u16 sA[128 * 32];
  __shared__ u16 sB[128 * 32];
  int tid = threadIdx.x;
  int lane = tid & 63, wv = tid >> 6;
  int quad = lane >> 4, lm = lane & 15;
  int wr = wv >> 1, wc = wv & 1;
  long m0 = (long)blockIdx.x * 128, n0 = (long)blockIdx.y * 128;
  int z = blockIdx.z;
  if (z >= zsplit) { A = A2 + (long)(z - zsplit) * Abs; C = C2 + (long)(z - zsplit) * Cbs; }
  else             { A = A  + (long)z * Abs;            C = C  + (long)z * Cbs; }
  B += (long)z * Bbs;
  if (res) res += (long)z * Rbs;

  f32x4 acc[4][4] = {};

  int srow = wv * 16 + (lane >> 2);
  int sch = (lane & 3) * 8;
  const u16* Ap = A + (m0 + srow) * (long)lda + sch;
  const u16* Bp = B + (n0 + srow) * (long)ldb + sch;
  u16* lA = &sA[wv * 16 * 32];
  u16* lB = &sB[wv * 16 * 32];

  for (int k0 = 0; k0 < K; k0 += 32) {
    gload_lds16(Ap + k0, lA);
    gload_lds16(Ap + 64 * (long)lda + k0, lA + 64 * 32);
    gload_lds16(Bp + k0, lB);
    gload_lds16(Bp + 64 * (long)ldb + k0, lB + 64 * 32);
    __syncthreads();
    bf16x8 af[4], bfr[4];
    #pragma unroll
    for (int mi = 0; mi < 4; mi++)
      af[mi] = *(const bf16x8*)&sA[(wr * 64 + mi * 16 + lm) * 32 + quad * 8];
    #pragma unroll
    for (int ni = 0; ni < 4; ni++)
      bfr[ni] = *(const bf16x8*)&sB[(wc * 64 + ni * 16 + lm) * 32 + quad * 8];
    #pragma unroll
    for (int mi = 0; mi < 4; mi++)
      #pragma unroll
      for (int ni = 0; ni < 4; ni++)
        acc[mi][ni] = __builtin_amdgcn_mfma_f32_16x16x32_bf16(af[mi], bfr[ni], acc[mi][ni], 0, 0, 0);
    __syncthreads();
  }

  #pragma unroll
  for (int mi = 0; mi < 4; mi++) {
    #pragma unroll
    for (int ni = 0; ni < 4; ni++) {
      int col = (int)n0 + wc * 64 + ni * 16 + lm;
      float bv = bias ? bias[(long)z * bias_bs + col] : 0.0f;
      #pragma unroll
      for (int r = 0; r < 4; r++) {
        long rowg = m0 + wr * 64 + mi * 16 + quad * 4 + r;
        float v = acc[mi][ni][r] * scale + bv;
        if (res) v += res[rowg * (long)ldr + col];
        if constexpr (sizeof(CT) == 2) C[rowg * (long)ldc + col] = f2bf(v);
        else                           C[rowg * (long)ldc + col] = v;
      }
    }
  }
}

// ---------------- grouped conv1d via MFMA ----------------
__global__ __launch_bounds__(256)
void conv_mfma(const u16* __restrict__ xb, const u16* __restrict__ wt,
               const float* __restrict__ cb, u16* __restrict__ out) {
  __shared__ u16 sx[130][72];
  int s0 = blockIdx.x * 128;
  int g = blockIdx.y;
  int b = blockIdx.z;
  int tid = threadIdx.x, lane = tid & 63, wv = tid >> 6;
  int quad = lane >> 4, lm = lane & 15;

  for (int idx = tid; idx < 130 * 16; idx += 256) {
    int r = idx >> 4, c4 = (idx & 15) * 4;
    int s = s0 - 1 + r;
    ushort4 v;
    if (s >= 0 && s < Sn) v = *(const ushort4*)&xb[((long)b * Sn + s) * Dn + g * 64 + c4];
    else { v.x = 0; v.y = 0; v.z = 0; v.w = 0; }
    *(ushort4*)&sx[r][c4] = v;
  }
  __syncthreads();

  f32x4 acc[2][4] = {};
  const u16* wg = wt + (long)g * 64 * 192;
  #pragma unroll
  for (int ks = 0; ks < 6; ks++) {
    int t = ks >> 1;
    int i0 = (ks & 1) * 32 + quad * 8;
    bf16x8 a0 = *(const bf16x8*)&sx[wv * 32 + lm + t][i0];
    bf16x8 a1 = *(const bf16x8*)&sx[wv * 32 + 16 + lm + t][i0];
    #pragma unroll
    for (int nf = 0; nf < 4; nf++) {
      bf16x8 bf = *(const bf16x8*)&wg[(nf * 16 + lm) * 192 + ks * 32 + quad * 8];
      acc[0][nf] = __builtin_amdgcn_mfma_f32_16x16x32_bf16(a0, bf, acc[0][nf], 0, 0, 0);
      acc[1][nf] = __builtin_amdgcn_mfma_f32_16x16x32_bf16(a1, bf, acc[1][nf], 0, 0, 0);
    }
  }
  #pragma unroll
  for (int mi = 0; mi < 2; mi++) {
    #pragma unroll
    for (int nf = 0; nf < 4; nf++) {
      int col = g * 64 + nf * 16 + lm;
      float bias = cb[col];
      #pragma unroll
      for (int r = 0; r < 4; r++) {
        int row = wv * 32 + mi * 16 + quad * 4 + r;
        out[((long)b * Sn + s0 + row) * Dn + col] = f2bf(acc[mi][nf][r] + bias);
      }
    }
  }
}

// ---------------- layernorm (ddof=1, eps on std); optional add; in-place safe ----
__global__ __launch_bounds__(256)
void ln_kernel(const u16* __restrict__ a, const u16* __restrict__ b2,
               const float* __restrict__ gamma, const float* __restrict__ beta,
               u16* __restrict__ out) {
  __shared__ float red[4];
  long row = blockIdx.x;
  int tid = threadIdx.x;
  long base = row * Dn + tid * 4;
  ushort4 av = *(const ushort4*)&a[base];
  float v0 = bf2f(av.x), v1 = bf2f(av.y), v2 = bf2f(av.z), v3 = bf2f(av.w);
  if (b2) {
    ushort4 bv4 = *(const ushort4*)&b2[base];
    v0 += bf2f(bv4.x); v1 += bf2f(bv4.y); v2 += bf2f(bv4.z); v3 += bf2f(bv4.w);
  }
  float s = block_allreduce_sum(v0 + v1 + v2 + v3, red, tid);
  float mean = s * (1.0f / 1024.0f);
  float d0 = v0 - mean, d1 = v1 - mean, d2 = v2 - mean, d3 = v3 - mean;
  float sq = block_allreduce_sum(d0 * d0 + d1 * d1 + d2 * d2 + d3 * d3, red, tid);
  float inv = 1.0f / (sqrtf(sq * (1.0f / 1023.0f)) + 1e-6f);
  float4 gv = *(const float4*)&gamma[tid * 4];
  float4 bev = *(const float4*)&beta[tid * 4];
  ushort4 o;
  o.x = f2bf(gv.x * d0 * inv + bev.x);
  o.y = f2bf(gv.y * d1 * inv + bev.y);
  o.z = f2bf(gv.z * d2 * inv + bev.z);
  o.w = f2bf(gv.w * d3 * inv + bev.w);
  *(ushort4*)&out[base] = o;
}

// ---------------- softmax over bf16 rows of 2048, in place; split base ----------
__global__ __launch_bounds__(256)
void softmax_bf16(u16* __restrict__ pa, u16* __restrict__ pb, int rowsplit) {
  __shared__ float red[4];
  long row = blockIdx.x;
  u16* p = (row < rowsplit) ? pa + row * 2048 : pb + (row - rowsplit) * 2048;
  int tid = threadIdx.x;
  ushort4 a = *(const ushort4*)&p[tid * 8];
  ushort4 b = *(const ushort4*)&p[tid * 8 + 4];
  float f0 = bf2f(a.x), f1 = bf2f(a.y), f2 = bf2f(a.z), f3 = bf2f(a.w);
  float f4 = bf2f(b.x), f5 = bf2f(b.y), f6 = bf2f(b.z), f7 = bf2f(b.w);
  float m = fmaxf(fmaxf(fmaxf(f0, f1), fmaxf(f2, f3)),
                  fmaxf(fmaxf(f4, f5), fmaxf(f6, f7)));
  m = block_allreduce_max(m, red, tid);
  float e0 = __expf(f0 - m), e1 = __expf(f1 - m), e2 = __expf(f2 - m), e3 = __expf(f3 - m);
  float e4 = __expf(f4 - m), e5 = __expf(f5 - m), e6 = __expf(f6 - m), e7 = __expf(f7 - m);
  float s = block_allreduce_sum(e0 + e1 + e2 + e3 + e4 + e5 + e6 + e7, red, tid);
  float inv = 1.0f / s;
  ushort4 o1, o2;
  o1.x = f2bf(e0 * inv); o1.y = f2bf(e1 * inv); o1.z = f2bf(e2 * inv); o1.w = f2bf(e3 * inv);
  o2.x = f2bf(e4 * inv); o2.y = f2bf(e5 * inv); o2.z = f2bf(e6 * inv); o2.w = f2bf(e7 * inv);
  *(ushort4*)&p[tid * 8] = o1;
  *(ushort4*)&p[tid * 8 + 4] = o2;
}

// ---------------- workspace layout ----------------
static const size_t OFF_WT    = 0;
static const size_t OFF_QKVB  = 8ull << 20;
static const size_t OFF_WCONV = (8ull << 20) + (64 << 10);
static const size_t OFF_Q     = 9ull << 20;
static const size_t OFF_K     = 25ull << 20;
static const size_t OFF_V     = 41ull << 20;
static const size_t OFF_PW    = 57ull << 20;   // P batches 2,3 (16 MB) — primary path

extern "C" void kernel_launch(void* const* d_in, const int* in_sizes, int n_in,
                              void* d_out, int out_size, void* d_ws, size_t ws_size,
                              hipStream_t stream) {
  const float* x     = (const float*)d_in[0];
  const float* Wq    = (const float*)d_in[1];
  const float* bq    = (const float*)d_in[2];
  const float* Wk    = (const float*)d_in[3];
  const float* Wv    = (const float*)d_in[4];
  const float* bv    = (const float*)d_in[5];
  const float* cw    = (const float*)d_in[6];
  const float* cb    = (const float*)d_in[7];
  const float* gamma = (const float*)d_in[8];
  const float* beta  = (const float*)d_in[9];
  const float* Wo    = (const float*)d_in[10];
  const float* bo    = (const float*)d_in[11];
  float* out = (float*)d_out;
  char* ws = (char*)d_ws;

  u16*   wT    = (u16*)(ws + OFF_WT);
  float* qkvb  = (float*)(ws + OFF_QKVB);
  u16*   wconv = (u16*)(ws + OFF_WCONV);
  u16*   Qb    = (u16*)(ws + OFF_Q);
  u16*   Kb    = (u16*)(ws + OFF_K);
  u16*   Vb    = (u16*)(ws + OFF_V);
  u16*   Pw    = (u16*)(ws + OFF_PW);
  u16*   xb    = (u16*)d_out;               // dead after conv; then P batches 0,1
  u16*   Pd    = (u16*)d_out;
  u16*   vt    = (u16*)d_out + 8388608;     // V^T, dead after PV
  u16*   conv  = Vb;
  u16*   attn  = Qb;
  u16*   combined = Kb;
  const long PBS = (long)Sn * Sn;           // 4M elems per batch

  dim3 tb(256);

  // prep
  transpose_cvt4<<<dim3(16, 16, 4), tb, 0, stream>>>(Wq, Wk, Wv, Wo, wT);
  concat_bias<<<dim3(12), tb, 0, stream>>>(bq, bv, qkvb);
  conv_w_prep<<<dim3(1024), dim3(192), 0, stream>>>(cw, wconv);
  cvt_f32_bf16<<<dim3(8192), tb, 0, stream>>>(x, xb, 8388608);

  // QKV (z = Q,K,V planes)
  gemm_nt<u16><<<dim3(64, 8, 3), tb, 0, stream>>>(
      xb, nullptr, 0, 1024, wT, 1048576, 1024, Qb, (u16*)nullptr, 8388608, 1024,
      99, 1024, 1.0f, qkvb, 1024, nullptr, 0, 0);
  // V^T per batch -> vt
  transpose_u16<<<dim3(16, 32, 4), tb, 0, stream>>>(
      Vb, vt, 1024, 2048, (long)Sn * Dn, (long)Dn * Sn);
  // conv (MFMA) -> conv region; LN in place. xb dead after this.
  conv_mfma<<<dim3(16, 16, 4), tb, 0, stream>>>(xb, wconv, cb, conv);
  ln_kernel<<<dim3(8192), tb, 0, stream>>>(conv, nullptr, gamma, beta, conv);

  if (ws_size >= (73ull << 20)) {
    // single-launch attention: P batches 0,1 (rows 0..4095) in d_out, 2,3 in ws
    gemm_nt<u16><<<dim3(16, 16, 4), tb, 0, stream>>>(
        Qb, Qb + 2 * (long)Sn * Dn, (long)Sn * Dn, 1024,
        Kb, (long)Sn * Dn, 1024,
        Pd, Pw, PBS, 2048,
        2, 1024, 0.03125f, nullptr, 0, nullptr, 0, 0);
    softmax_bf16<<<dim3(8192), tb, 0, stream>>>(Pd, Pw, 4096);  // 8192 rows total
    gemm_nt<u16><<<dim3(16, 8, 4), tb, 0, stream>>>(
        Pd, Pw, PBS, 2048,
        vt, (long)Dn * Sn, 2048,
        attn, attn + 2 * (long)Sn * Dn, (long)Sn * Dn, 1024,
        2, 2048, 1.0f, nullptr, 0, nullptr, 0, 0);
  } else {
    // fallback: 2 chunks of 2 batches, P in d_out only (4096 rows per chunk)
    for (int c = 0; c < 2; c++) {
      long off = (long)c * 2 * Sn * Dn;
      gemm_nt<u16><<<dim3(16, 16, 2), tb, 0, stream>>>(
          Qb + off, nullptr, (long)Sn * Dn, 1024, Kb + off, (long)Sn * Dn, 1024,
          Pd, (u16*)nullptr, PBS, 2048,
          99, 1024, 0.03125f, nullptr, 0, nullptr, 0, 0);
      softmax_bf16<<<dim3(4096), tb, 0, stream>>>(Pd, Pd, 4096);
      gemm_nt<u16><<<dim3(16, 8, 2), tb, 0, stream>>>(
          Pd, nullptr, PBS, 2048, vt + off, (long)Dn * Sn, 2048,
          attn + off, (u16*)nullptr, (long)Sn * Dn, 1024,
          99, 2048, 1.0f, nullptr, 0, nullptr, 0, 0);
    }
  }

  // combined = LN(conv + attn); out = combined @ Wo + bo + x
  ln_kernel<<<dim3(8192), tb, 0, stream>>>(conv, attn, gamma, beta, combined);
  gemm_nt<float><<<dim3(64, 8, 1), tb, 0, stream>>>(
      combined, nullptr, 0, 1024, wT + 3u * 1048576u, 0, 1024,
      out, (float*)nullptr, 0, 1024,
      99, 1024, 1.0f, bo, 0, x, 0, 1024);
}

// Round 7
// 359.362 us; speedup vs baseline: 1.8756x; 1.0668x over previous
//
#include <hip/hip_runtime.h>
#include <cstdint>

// DynamicConvAttention: B=4, S=2048, D=1024, NH=16 (groups), K=3
// f32 I/O, bf16 MFMA internal. 9 launches.
//
// ws (73 MB primary path):
//   wT      [0, 8 MB)        bf16 WqT,WkT,WvT,WoT (1M u16 each)
//   qkvb    [8 MB, +12 KB)   f32 concat bias [bq|0|bv]
//   wt_conv [8 MB+64KB, +384KB) bf16 conv weights [1024][192], k=t*64+i
//   Q       [9, 25 MB)  bf16 [8192][1024]  (attn overwrites after scores)
//   K       [25, 41 MB) bf16               (combined after scores)
//   V       [41, 57 MB) bf16               (conv buffer after V->vt)
//   Pw      [57, 73 MB) bf16 P batches 2,3 (4096 rows)
// d_out (33.5 MB f32) as scratch:
//   xb = d_out[0:16.78MB)    bf16 x (dead after conv) -> then P batches 0,1
//   vt = d_out[+8388608 u16] bf16 V^T [4][1024][2048] (dead after PV)

#define DEV __device__ __forceinline__

typedef unsigned short u16;
typedef __attribute__((ext_vector_type(8))) short bf16x8;
typedef __attribute__((ext_vector_type(4))) float f32x4;

static const int Sn = 2048, Dn = 1024;

DEV float bf2f(u16 u) { union { unsigned int i; float f; } w; w.i = ((unsigned int)u) << 16; return w.f; }
DEV u16 f2bf(float f) {
  union { float f; unsigned int i; } w; w.f = f;
  unsigned int x = w.i;
  return (u16)((x + 0x7FFFu + ((x >> 16) & 1u)) >> 16);
}

DEV void gload_lds16(const u16* gsrc, u16* lds_dst) {
  __builtin_amdgcn_global_load_lds(
      (const __attribute__((address_space(1))) void*)gsrc,
      (__attribute__((address_space(3))) void*)lds_dst,
      16, 0, 0);
}

DEV float block_allreduce_sum(float v, float* red, int tid) {
  #pragma unroll
  for (int o = 32; o > 0; o >>= 1) v += __shfl_down(v, o, 64);
  __syncthreads();
  if ((tid & 63) == 0) red[tid >> 6] = v;
  __syncthreads();
  return red[0] + red[1] + red[2] + red[3];
}

DEV float block_allreduce_max(float v, float* red, int tid) {
  #pragma unroll
  for (int o = 32; o > 0; o >>= 1) v = fmaxf(v, __shfl_down(v, o, 64));
  __syncthreads();
  if ((tid & 63) == 0) red[tid >> 6] = v;
  __syncthreads();
  return fmaxf(fmaxf(red[0], red[1]), fmaxf(red[2], red[3]));
}

// ================= prep_all: fused prologue =================
// blocks 0..1023    : weight transpose+cvt (4 weights x 256 tiles of 64x64)
// blocks 1024..1039 : conv weight prep (64 oc each)
// block  1040       : qkv bias concat
// blocks 1041..9232 : x f32->bf16 (1024 elems each)
__global__ __launch_bounds__(256)
void prep_all(const float* __restrict__ Wq, const float* __restrict__ Wk,
              const float* __restrict__ Wv, const float* __restrict__ Wo,
              u16* __restrict__ wT,
              const float* __restrict__ bq, const float* __restrict__ bv,
              float* __restrict__ qkvb,
              const float* __restrict__ cw, u16* __restrict__ wconv,
              const float* __restrict__ x, u16* __restrict__ xb) {
  __shared__ u16 sm[64][68];
  int blk = blockIdx.x;
  int tid = threadIdx.x;
  if (blk < 1024) {
    int w = blk >> 8, t = blk & 255;
    const float* src = (w == 0) ? Wq : (w == 1) ? Wk : (w == 2) ? Wv : Wo;
    u16* dst = wT + (size_t)w * 1048576u;
    int i0 = (t >> 4) << 6, j0 = (t & 15) << 6;
    int tx = tid & 15, r0 = tid >> 4;
    #pragma unroll
    for (int rr = r0; rr < 64; rr += 16) {
      float4 v = *(const float4*)&src[(long)(i0 + rr) * 1024 + j0 + tx * 4];
      sm[rr][tx*4+0] = f2bf(v.x); sm[rr][tx*4+1] = f2bf(v.y);
      sm[rr][tx*4+2] = f2bf(v.z); sm[rr][tx*4+3] = f2bf(v.w);
    }
    __syncthreads();
    #pragma unroll
    for (int cc = r0; cc < 64; cc += 16) {
      ushort4 o;
      o.x = sm[tx*4+0][cc]; o.y = sm[tx*4+1][cc];
      o.z = sm[tx*4+2][cc]; o.w = sm[tx*4+3][cc];
      *(ushort4*)&dst[(long)(j0 + cc) * 1024 + i0 + tx * 4] = o;
    }
  } else if (blk < 1040) {
    int oc0 = (blk - 1024) * 64;
    for (int idx = tid; idx < 64 * 192; idx += 256) {
      int oc = oc0 + idx / 192; int k = idx % 192;
      int t = k >> 6, i = k & 63;
      wconv[(long)oc * 192 + k] = f2bf(cw[(long)oc * 192 + i * 3 + t]);
    }
  } else if (blk == 1040) {
    for (int j = tid; j < 3072; j += 256) {
      float v = 0.0f;
      if (j < 1024) v = bq[j];
      else if (j >= 2048) v = bv[j - 2048];
      qkvb[j] = v;
    }
  } else {
    int i = (blk - 1041) * 1024 + tid * 4;
    float4 v = *(const float4*)&x[i];
    ushort4 o;
    o.x = f2bf(v.x); o.y = f2bf(v.y); o.z = f2bf(v.z); o.w = f2bf(v.w);
    *(ushort4*)&xb[i] = o;
  }
}

// ================= NT GEMM, BK=64 split-halves (m97 staging per half) ======
// 128x128 tile, 256 threads (4 waves 2x2 of 64x64), mfma 16x16x32 bf16.
// sA/sB: [2][128][32] u16 — each half uses the proven BK=32 pattern
// (row stride 64 B -> 2-way LDS aliasing only). One barrier pair per 64 K.
template<typename CT>
__global__ __launch_bounds__(256, 2)
void gemm_nt(const u16* __restrict__ A, const u16* __restrict__ A2, long Abs, int lda,
             const u16* __restrict__ B, long Bbs, int ldb,
             CT* __restrict__ C, CT* __restrict__ C2, long Cbs, int ldc,
             int zsplit, int K, float scale,
             const float* __restrict__ bias, int bias_bs,
             const float* __restrict__ res, long Rbs, int ldr) {
  __shared__ u16 sA[2][128 * 32];
  __shared__ u16 sB[2][128 * 32];
  int tid = threadIdx.x;
  int lane = tid & 63, wv = tid >> 6;
  int quad = lane >> 4, lm = lane & 15;
  int wr = wv >> 1, wc = wv & 1;
  long m0 = (long)blockIdx.x * 128, n0 = (long)blockIdx.y * 128;
  int z = blockIdx.z;
  if (z >= zsplit) { A = A2 + (long)(z - zsplit) * Abs; C = C2 + (long)(z - zsplit) * Cbs; }
  else             { A = A  + (long)z * Abs;            C = C  + (long)z * Cbs; }
  B += (long)z * Bbs;
  if (res) res += (long)z * Rbs;

  f32x4 acc[4][4] = {};

  int srow = wv * 16 + (lane >> 2);
  int sch = (lane & 3) * 8;
  const u16* Ap = A + (m0 + srow) * (long)lda + sch;
  const u16* Bp = B + (n0 + srow) * (long)ldb + sch;
  const int lofs = wv * 16 * 32;

  for (int k0 = 0; k0 < K; k0 += 64) {
    #pragma unroll
    for (int h = 0; h < 2; h++) {
      int kh = k0 + h * 32;
      gload_lds16(Ap + kh, &sA[h][lofs]);
      gload_lds16(Ap + 64 * (long)lda + kh, &sA[h][lofs + 64 * 32]);
      gload_lds16(Bp + kh, &sB[h][lofs]);
      gload_lds16(Bp + 64 * (long)ldb + kh, &sB[h][lofs + 64 * 32]);
    }
    __syncthreads();
    #pragma unroll
    for (int h = 0; h < 2; h++) {
      bf16x8 af[4], bfr[4];
      #pragma unroll
      for (int mi = 0; mi < 4; mi++)
        af[mi] = *(const bf16x8*)&sA[h][(wr * 64 + mi * 16 + lm) * 32 + quad * 8];
      #pragma unroll
      for (int ni = 0; ni < 4; ni++)
        bfr[ni] = *(const bf16x8*)&sB[h][(wc * 64 + ni * 16 + lm) * 32 + quad * 8];
      #pragma unroll
      for (int mi = 0; mi < 4; mi++)
        #pragma unroll
        for (int ni = 0; ni < 4; ni++)
          acc[mi][ni] = __builtin_amdgcn_mfma_f32_16x16x32_bf16(af[mi], bfr[ni], acc[mi][ni], 0, 0, 0);
    }
    __syncthreads();
  }

  // C/D layout: col=lane&15, row=quad*4+reg (m89/m91 verified)
  #pragma unroll
  for (int mi = 0; mi < 4; mi++) {
    #pragma unroll
    for (int ni = 0; ni < 4; ni++) {
      int col = (int)n0 + wc * 64 + ni * 16 + lm;
      float bv = bias ? bias[(long)z * bias_bs + col] : 0.0f;
      #pragma unroll
      for (int r = 0; r < 4; r++) {
        long rowg = m0 + wr * 64 + mi * 16 + quad * 4 + r;
        float v = acc[mi][ni][r] * scale + bv;
        if (res) v += res[rowg * (long)ldr + col];
        if constexpr (sizeof(CT) == 2) C[rowg * (long)ldc + col] = f2bf(v);
        else                           C[rowg * (long)ldc + col] = v;
      }
    }
  }
}

// ================= mid_all: conv MFMA + V^T transpose in one launch ========
// blocks 0..1023    : conv (s-tile = blk&15, g = (blk>>4)&15, b = blk>>8)
// blocks 1024..3071 : V^T 64x64 tiles (b = t>>9; x = t&15, y = (t>>4)&31)
__global__ __launch_bounds__(256)
void mid_all(const u16* __restrict__ xb, const u16* __restrict__ wt,
             const float* __restrict__ cb, u16* __restrict__ convo,
             const u16* __restrict__ Vb, u16* __restrict__ vt) {
  __shared__ u16 smem[9360];   // conv: 130x72 u16; transpose: 64x68 u16
  int blk = blockIdx.x;
  int tid = threadIdx.x;
  if (blk < 1024) {
    u16 (*sx)[72] = (u16(*)[72])smem;
    int s0 = (blk & 15) * 128;
    int g = (blk >> 4) & 15;
    int b = blk >> 8;
    int lane = tid & 63, wv = tid >> 6;
    int quad = lane >> 4, lm = lane & 15;
    for (int idx = tid; idx < 130 * 16; idx += 256) {
      int r = idx >> 4, c4 = (idx & 15) * 4;
      int s = s0 - 1 + r;
      ushort4 v;
      if (s >= 0 && s < Sn) v = *(const ushort4*)&xb[((long)b * Sn + s) * Dn + g * 64 + c4];
      else { v.x = 0; v.y = 0; v.z = 0; v.w = 0; }
      *(ushort4*)&sx[r][c4] = v;
    }
    __syncthreads();
    f32x4 acc[2][4] = {};
    const u16* wg = wt + (long)g * 64 * 192;
    #pragma unroll
    for (int ks = 0; ks < 6; ks++) {
      int t = ks >> 1;
      int i0 = (ks & 1) * 32 + quad * 8;
      bf16x8 a0 = *(const bf16x8*)&sx[wv * 32 + lm + t][i0];
      bf16x8 a1 = *(const bf16x8*)&sx[wv * 32 + 16 + lm + t][i0];
      #pragma unroll
      for (int nf = 0; nf < 4; nf++) {
        bf16x8 bf = *(const bf16x8*)&wg[(nf * 16 + lm) * 192 + ks * 32 + quad * 8];
        acc[0][nf] = __builtin_amdgcn_mfma_f32_16x16x32_bf16(a0, bf, acc[0][nf], 0, 0, 0);
        acc[1][nf] = __builtin_amdgcn_mfma_f32_16x16x32_bf16(a1, bf, acc[1][nf], 0, 0, 0);
      }
    }
    #pragma unroll
    for (int mi = 0; mi < 2; mi++) {
      #pragma unroll
      for (int nf = 0; nf < 4; nf++) {
        int col = g * 64 + nf * 16 + lm;
        float bias = cb[col];
        #pragma unroll
        for (int r = 0; r < 4; r++) {
          int row = wv * 32 + mi * 16 + quad * 4 + r;
          convo[((long)b * Sn + s0 + row) * Dn + col] = f2bf(acc[mi][nf][r] + bias);
        }
      }
    }
  } else {
    u16 (*sm)[68] = (u16(*)[68])smem;
    int t = blk - 1024;
    int b = t >> 9, r = t & 511;
    int j0 = (r & 15) << 6, i0 = ((r >> 4) & 31) << 6;
    const u16* s = Vb + (long)b * Sn * Dn;
    u16* d = vt + (long)b * Dn * Sn;
    int tx = tid & 15, r0 = tid >> 4;
    #pragma unroll
    for (int rr = r0; rr < 64; rr += 16) {
      ushort4 v = *(const ushort4*)&s[(long)(i0 + rr) * 1024 + j0 + tx * 4];
      sm[rr][tx*4+0] = v.x; sm[rr][tx*4+1] = v.y; sm[rr][tx*4+2] = v.z; sm[rr][tx*4+3] = v.w;
    }
    __syncthreads();
    #pragma unroll
    for (int cc = r0; cc < 64; cc += 16) {
      ushort4 o;
      o.x = sm[tx*4+0][cc]; o.y = sm[tx*4+1][cc];
      o.z = sm[tx*4+2][cc]; o.w = sm[tx*4+3][cc];
      *(ushort4*)&d[(long)(j0 + cc) * 2048 + i0 + tx * 4] = o;
    }
  }
}

// ================= layernorm (ddof=1, eps on std); optional add; in-place ==
__global__ __launch_bounds__(256)
void ln_kernel(const u16* __restrict__ a, const u16* __restrict__ b2,
               const float* __restrict__ gamma, const float* __restrict__ beta,
               u16* __restrict__ out) {
  __shared__ float red[4];
  long row = blockIdx.x;
  int tid = threadIdx.x;
  long base = row * Dn + tid * 4;
  ushort4 av = *(const ushort4*)&a[base];
  float v0 = bf2f(av.x), v1 = bf2f(av.y), v2 = bf2f(av.z), v3 = bf2f(av.w);
  if (b2) {
    ushort4 bv4 = *(const ushort4*)&b2[base];
    v0 += bf2f(bv4.x); v1 += bf2f(bv4.y); v2 += bf2f(bv4.z); v3 += bf2f(bv4.w);
  }
  float s = block_allreduce_sum(v0 + v1 + v2 + v3, red, tid);
  float mean = s * (1.0f / 1024.0f);
  float d0 = v0 - mean, d1 = v1 - mean, d2 = v2 - mean, d3 = v3 - mean;
  float sq = block_allreduce_sum(d0 * d0 + d1 * d1 + d2 * d2 + d3 * d3, red, tid);
  float inv = 1.0f / (sqrtf(sq * (1.0f / 1023.0f)) + 1e-6f);
  float4 gv = *(const float4*)&gamma[tid * 4];
  float4 bev = *(const float4*)&beta[tid * 4];
  ushort4 o;
  o.x = f2bf(gv.x * d0 * inv + bev.x);
  o.y = f2bf(gv.y * d1 * inv + bev.y);
  o.z = f2bf(gv.z * d2 * inv + bev.z);
  o.w = f2bf(gv.w * d3 * inv + bev.w);
  *(ushort4*)&out[base] = o;
}

// ================= softmax over bf16 rows of 2048, in place; split base ====
__global__ __launch_bounds__(256)
void softmax_bf16(u16* __restrict__ pa, u16* __restrict__ pb, int rowsplit) {
  __shared__ float red[4];
  long row = blockIdx.x;
  u16* p = (row < rowsplit) ? pa + row * 2048 : pb + (row - rowsplit) * 2048;
  int tid = threadIdx.x;
  ushort4 a = *(const ushort4*)&p[tid * 8];
  ushort4 b = *(const ushort4*)&p[tid * 8 + 4];
  float f0 = bf2f(a.x), f1 = bf2f(a.y), f2 = bf2f(a.z), f3 = bf2f(a.w);
  float f4 = bf2f(b.x), f5 = bf2f(b.y), f6 = bf2f(b.z), f7 = bf2f(b.w);
  float m = fmaxf(fmaxf(fmaxf(f0, f1), fmaxf(f2, f3)),
                  fmaxf(fmaxf(f4, f5), fmaxf(f6, f7)));
  m = block_allreduce_max(m, red, tid);
  float e0 = __expf(f0 - m), e1 = __expf(f1 - m), e2 = __expf(f2 - m), e3 = __expf(f3 - m);
  float e4 = __expf(f4 - m), e5 = __expf(f5 - m), e6 = __expf(f6 - m), e7 = __expf(f7 - m);
  float s = block_allreduce_sum(e0 + e1 + e2 + e3 + e4 + e5 + e6 + e7, red, tid);
  float inv = 1.0f / s;
  ushort4 o1, o2;
  o1.x = f2bf(e0 * inv); o1.y = f2bf(e1 * inv); o1.z = f2bf(e2 * inv); o1.w = f2bf(e3 * inv);
  o2.x = f2bf(e4 * inv); o2.y = f2bf(e5 * inv); o2.z = f2bf(e6 * inv); o2.w = f2bf(e7 * inv);
  *(ushort4*)&p[tid * 8] = o1;
  *(ushort4*)&p[tid * 8 + 4] = o2;
}

// ================= workspace layout =================
static const size_t OFF_WT    = 0;
static const size_t OFF_QKVB  = 8ull << 20;
static const size_t OFF_WCONV = (8ull << 20) + (64 << 10);
static const size_t OFF_Q     = 9ull << 20;
static const size_t OFF_K     = 25ull << 20;
static const size_t OFF_V     = 41ull << 20;
static const size_t OFF_PW    = 57ull << 20;

extern "C" void kernel_launch(void* const* d_in, const int* in_sizes, int n_in,
                              void* d_out, int out_size, void* d_ws, size_t ws_size,
                              hipStream_t stream) {
  const float* x     = (const float*)d_in[0];
  const float* Wq    = (const float*)d_in[1];
  const float* bq    = (const float*)d_in[2];
  const float* Wk    = (const float*)d_in[3];
  const float* Wv    = (const float*)d_in[4];
  const float* bv    = (const float*)d_in[5];
  const float* cw    = (const float*)d_in[6];
  const float* cb    = (const float*)d_in[7];
  const float* gamma = (const float*)d_in[8];
  const float* beta  = (const float*)d_in[9];
  const float* Wo    = (const float*)d_in[10];
  const float* bo    = (const float*)d_in[11];
  float* out = (float*)d_out;
  char* ws = (char*)d_ws;

  u16*   wT    = (u16*)(ws + OFF_WT);
  float* qkvb  = (float*)(ws + OFF_QKVB);
  u16*   wconv = (u16*)(ws + OFF_WCONV);
  u16*   Qb    = (u16*)(ws + OFF_Q);
  u16*   Kb    = (u16*)(ws + OFF_K);
  u16*   Vb    = (u16*)(ws + OFF_V);
  u16*   Pw    = (u16*)(ws + OFF_PW);
  u16*   xb    = (u16*)d_out;               // dead after conv; then P batches 0,1
  u16*   Pd    = (u16*)d_out;
  u16*   vt    = (u16*)d_out + 8388608;     // V^T, dead after PV
  u16*   conv  = Vb;
  u16*   attn  = Qb;
  u16*   combined = Kb;
  const long PBS = (long)Sn * Sn;

  dim3 tb(256);

  // 1. fused prologue (weights T, conv w, bias, x cvt)
  prep_all<<<dim3(9233), tb, 0, stream>>>(Wq, Wk, Wv, Wo, wT, bq, bv, qkvb,
                                          cw, wconv, x, xb);
  // 2. QKV (z = Q,K,V planes)
  gemm_nt<u16><<<dim3(64, 8, 3), tb, 0, stream>>>(
      xb, nullptr, 0, 1024, wT, 1048576, 1024, Qb, (u16*)nullptr, 8388608, 1024,
      99, 1024, 1.0f, qkvb, 1024, nullptr, 0, 0);
  // 3. conv MFMA + V^T (independent; one launch)
  mid_all<<<dim3(3072), tb, 0, stream>>>(xb, wconv, cb, conv, Vb, vt);
  // 4. LN(conv) in place
  ln_kernel<<<dim3(8192), tb, 0, stream>>>(conv, nullptr, gamma, beta, conv);

  if (ws_size >= (73ull << 20)) {
    // 5-7. single-launch attention: P batches 0,1 in d_out, 2,3 in ws
    gemm_nt<u16><<<dim3(16, 16, 4), tb, 0, stream>>>(
        Qb, Qb + 2 * (long)Sn * Dn, (long)Sn * Dn, 1024,
        Kb, (long)Sn * Dn, 1024,
        Pd, Pw, PBS, 2048,
        2, 1024, 0.03125f, nullptr, 0, nullptr, 0, 0);
    softmax_bf16<<<dim3(8192), tb, 0, stream>>>(Pd, Pw, 4096);  // 8192 rows
    gemm_nt<u16><<<dim3(16, 8, 4), tb, 0, stream>>>(
        Pd, Pw, PBS, 2048,
        vt, (long)Dn * Sn, 2048,
        attn, attn + 2 * (long)Sn * Dn, (long)Sn * Dn, 1024,
        2, 2048, 1.0f, nullptr, 0, nullptr, 0, 0);
  } else {
    for (int c = 0; c < 2; c++) {
      long off = (long)c * 2 * Sn * Dn;
      gemm_nt<u16><<<dim3(16, 16, 2), tb, 0, stream>>>(
          Qb + off, nullptr, (long)Sn * Dn, 1024, Kb + off, (long)Sn * Dn, 1024,
          Pd, (u16*)nullptr, PBS, 2048,
          99, 1024, 0.03125f, nullptr, 0, nullptr, 0, 0);
      softmax_bf16<<<dim3(4096), tb, 0, stream>>>(Pd, Pd, 4096);
      gemm_nt<u16><<<dim3(16, 8, 2), tb, 0, stream>>>(
          Pd, nullptr, PBS, 2048, vt + off, (long)Dn * Sn, 2048,
          attn + off, (u16*)nullptr, (long)Sn * Dn, 1024,
          99, 2048, 1.0f, nullptr, 0, nullptr, 0, 0);
    }
  }

  // 8. combined = LN(conv + attn); 9. out = combined @ Wo + bo + x
  ln_kernel<<<dim3(8192), tb, 0, stream>>>(conv, attn, gamma, beta, combined);
  gemm_nt<float><<<dim3(64, 8, 1), tb, 0, stream>>>(
      combined, nullptr, 0, 1024, wT + 3u * 1048576u, 0, 1024,
      out, (float*)nullptr, 0, 1024,
      99, 1024, 1.0f, bo, 0, x, 0, 1024);
}

// Round 9
// 355.700 us; speedup vs baseline: 1.8949x; 1.0103x over previous
//
#include <hip/hip_runtime.h>
#include <cstdint>

// DynamicConvAttention: B=4, S=2048, D=1024, NH=16 (groups), K=3
// f32 I/O, bf16 MFMA internal. 7 launches (primary path).
//
// ws (73 MB primary path):
//   wT   [0, 8 MB)      bf16 WqT,WkT,WvT,WoT (1M u16 each)
//   qkvb [8 MB, +12 KB) f32 concat bias [bq|0|bv]
//   Q    [9, 25 MB)  bf16 [8192][1024]  (attn overwrites after scores)
//   K    [25, 41 MB) bf16               (combined after scores)
//   V    [41, 57 MB) bf16               (conv output AFTER V->vt completes)
//   Pw   [57, 73 MB) bf16 P batches 2,3 (4096 rows)
// d_out (33.5 MB f32) as scratch:
//   xb = d_out[0:16.78MB)    bf16 x (dead after QKV) -> then P batches 0,1
//   vt = d_out[+8388608 u16] bf16 V^T [4][1024][2048] (dead after PV)
//
// ORDERING (round-8 bug): conv output lives in Vb, so conv may only run
// AFTER V^T has consumed V (i.e. after post_qkv) — it rides the softmax
// launch. LN(conv) rides the PV launch.

#define DEV __device__ __forceinline__

typedef unsigned short u16;
typedef __attribute__((ext_vector_type(8))) short bf16x8;
typedef __attribute__((ext_vector_type(4))) float f32x4;

static const int Sn = 2048, Dn = 1024;

DEV float bf2f(u16 u) { union { unsigned int i; float f; } w; w.i = ((unsigned int)u) << 16; return w.f; }
DEV u16 f2bf(float f) {
  union { float f; unsigned int i; } w; w.f = f;
  unsigned int x = w.i;
  return (u16)((x + 0x7FFFu + ((x >> 16) & 1u)) >> 16);
}

DEV void gload_lds16(const u16* gsrc, u16* lds_dst) {
  __builtin_amdgcn_global_load_lds(
      (const __attribute__((address_space(1))) void*)gsrc,
      (__attribute__((address_space(3))) void*)lds_dst,
      16, 0, 0);
}

DEV float block_allreduce_sum(float v, float* red, int tid) {
  #pragma unroll
  for (int o = 32; o > 0; o >>= 1) v += __shfl_down(v, o, 64);
  __syncthreads();
  if ((tid & 63) == 0) red[tid >> 6] = v;
  __syncthreads();
  return red[0] + red[1] + red[2] + red[3];
}

DEV float block_allreduce_max(float v, float* red, int tid) {
  #pragma unroll
  for (int o = 32; o > 0; o >>= 1) v = fmaxf(v, __shfl_down(v, o, 64));
  __syncthreads();
  if ((tid & 63) == 0) red[tid >> 6] = v;
  __syncthreads();
  return fmaxf(fmaxf(red[0], red[1]), fmaxf(red[2], red[3]));
}

// ---- layernorm row body (torch-style: ddof=1, eps on std); in-place safe ----
DEV void ln_row(const u16* __restrict__ a, const u16* __restrict__ b2,
                const float* __restrict__ gamma, const float* __restrict__ beta,
                u16* __restrict__ out, long row, int tid, float* red) {
  long base = row * Dn + tid * 4;
  ushort4 av = *(const ushort4*)&a[base];
  float v0 = bf2f(av.x), v1 = bf2f(av.y), v2 = bf2f(av.z), v3 = bf2f(av.w);
  if (b2) {
    ushort4 bv4 = *(const ushort4*)&b2[base];
    v0 += bf2f(bv4.x); v1 += bf2f(bv4.y); v2 += bf2f(bv4.z); v3 += bf2f(bv4.w);
  }
  float s = block_allreduce_sum(v0 + v1 + v2 + v3, red, tid);
  float mean = s * (1.0f / 1024.0f);
  float d0 = v0 - mean, d1 = v1 - mean, d2 = v2 - mean, d3 = v3 - mean;
  float sq = block_allreduce_sum(d0 * d0 + d1 * d1 + d2 * d2 + d3 * d3, red, tid);
  float inv = 1.0f / (sqrtf(sq * (1.0f / 1023.0f)) + 1e-6f);
  float4 gv = *(const float4*)&gamma[tid * 4];
  float4 bev = *(const float4*)&beta[tid * 4];
  ushort4 o;
  o.x = f2bf(gv.x * d0 * inv + bev.x);
  o.y = f2bf(gv.y * d1 * inv + bev.y);
  o.z = f2bf(gv.z * d2 * inv + bev.z);
  o.w = f2bf(gv.w * d3 * inv + bev.w);
  *(ushort4*)&out[base] = o;
}

// ================= prep_all: weights T + bias + x cvt ==============
// blocks [0,1024)    : weight transpose+cvt (4 weights x 256 tiles 64x64)
// block  1024        : qkv bias concat
// blocks [1025,9217) : x f32->bf16 (1024 elems each)
__global__ __launch_bounds__(256)
void prep_all(const float* __restrict__ Wq, const float* __restrict__ Wk,
              const float* __restrict__ Wv, const float* __restrict__ Wo,
              u16* __restrict__ wT,
              const float* __restrict__ bq, const float* __restrict__ bv,
              float* __restrict__ qkvb,
              const float* __restrict__ x, u16* __restrict__ xb) {
  __shared__ u16 sm[64][68];
  int blk = blockIdx.x;
  int tid = threadIdx.x;
  if (blk < 1024) {
    int w = blk >> 8, t = blk & 255;
    const float* src = (w == 0) ? Wq : (w == 1) ? Wk : (w == 2) ? Wv : Wo;
    u16* dst = wT + (size_t)w * 1048576u;
    int i0 = (t >> 4) << 6, j0 = (t & 15) << 6;
    int tx = tid & 15, r0 = tid >> 4;
    #pragma unroll
    for (int rr = r0; rr < 64; rr += 16) {
      float4 v = *(const float4*)&src[(long)(i0 + rr) * 1024 + j0 + tx * 4];
      sm[rr][tx*4+0] = f2bf(v.x); sm[rr][tx*4+1] = f2bf(v.y);
      sm[rr][tx*4+2] = f2bf(v.z); sm[rr][tx*4+3] = f2bf(v.w);
    }
    __syncthreads();
    #pragma unroll
    for (int cc = r0; cc < 64; cc += 16) {
      ushort4 o;
      o.x = sm[tx*4+0][cc]; o.y = sm[tx*4+1][cc];
      o.z = sm[tx*4+2][cc]; o.w = sm[tx*4+3][cc];
      *(ushort4*)&dst[(long)(j0 + cc) * 1024 + i0 + tx * 4] = o;
    }
  } else if (blk == 1024) {
    for (int j = tid; j < 3072; j += 256) {
      float v = 0.0f;
      if (j < 1024) v = bq[j];
      else if (j >= 2048) v = bv[j - 2048];
      qkvb[j] = v;
    }
  } else {
    int i = (blk - 1025) * 1024 + tid * 4;
    float4 v = *(const float4*)&x[i];
    ushort4 o;
    o.x = f2bf(v.x); o.y = f2bf(v.y); o.z = f2bf(v.z); o.w = f2bf(v.w);
    *(ushort4*)&xb[i] = o;
  }
}

// ================= NT GEMM, BK=64 split-halves (proven r7 core) ============
template<typename CT>
__global__ __launch_bounds__(256, 2)
void gemm_nt(const u16* __restrict__ A, const u16* __restrict__ A2, long Abs, int lda,
             const u16* __restrict__ B, long Bbs, int ldb,
             CT* __restrict__ C, CT* __restrict__ C2, long Cbs, int ldc,
             int zsplit, int K, float scale,
             const float* __restrict__ bias, int bias_bs,
             const float* __restrict__ res, long Rbs, int ldr) {
  __shared__ u16 sA[2][128 * 32];
  __shared__ u16 sB[2][128 * 32];
  int tid = threadIdx.x;
  int lane = tid & 63, wv = tid >> 6;
  int quad = lane >> 4, lm = lane & 15;
  int wr = wv >> 1, wc = wv & 1;
  long m0 = (long)blockIdx.x * 128, n0 = (long)blockIdx.y * 128;
  int z = blockIdx.z;
  if (z >= zsplit) { A = A2 + (long)(z - zsplit) * Abs; C = C2 + (long)(z - zsplit) * Cbs; }
  else             { A = A  + (long)z * Abs;            C = C  + (long)z * Cbs; }
  B += (long)z * Bbs;
  if (res) res += (long)z * Rbs;

  f32x4 acc[4][4] = {};

  int srow = wv * 16 + (lane >> 2);
  int sch = (lane & 3) * 8;
  const u16* Ap = A + (m0 + srow) * (long)lda + sch;
  const u16* Bp = B + (n0 + srow) * (long)ldb + sch;
  const int lofs = wv * 16 * 32;

  for (int k0 = 0; k0 < K; k0 += 64) {
    #pragma unroll
    for (int h = 0; h < 2; h++) {
      int kh = k0 + h * 32;
      gload_lds16(Ap + kh, &sA[h][lofs]);
      gload_lds16(Ap + 64 * (long)lda + kh, &sA[h][lofs + 64 * 32]);
      gload_lds16(Bp + kh, &sB[h][lofs]);
      gload_lds16(Bp + 64 * (long)ldb + kh, &sB[h][lofs + 64 * 32]);
    }
    __syncthreads();
    #pragma unroll
    for (int h = 0; h < 2; h++) {
      bf16x8 af[4], bfr[4];
      #pragma unroll
      for (int mi = 0; mi < 4; mi++)
        af[mi] = *(const bf16x8*)&sA[h][(wr * 64 + mi * 16 + lm) * 32 + quad * 8];
      #pragma unroll
      for (int ni = 0; ni < 4; ni++)
        bfr[ni] = *(const bf16x8*)&sB[h][(wc * 64 + ni * 16 + lm) * 32 + quad * 8];
      #pragma unroll
      for (int mi = 0; mi < 4; mi++)
        #pragma unroll
        for (int ni = 0; ni < 4; ni++)
          acc[mi][ni] = __builtin_amdgcn_mfma_f32_16x16x32_bf16(af[mi], bfr[ni], acc[mi][ni], 0, 0, 0);
    }
    __syncthreads();
  }

  #pragma unroll
  for (int mi = 0; mi < 4; mi++) {
    #pragma unroll
    for (int ni = 0; ni < 4; ni++) {
      int col = (int)n0 + wc * 64 + ni * 16 + lm;
      float bv = bias ? bias[(long)z * bias_bs + col] : 0.0f;
      #pragma unroll
      for (int r = 0; r < 4; r++) {
        long rowg = m0 + wr * 64 + mi * 16 + quad * 4 + r;
        float v = acc[mi][ni][r] * scale + bv;
        if (res) v += res[rowg * (long)ldr + col];
        if constexpr (sizeof(CT) == 2) C[rowg * (long)ldc + col] = f2bf(v);
        else                           C[rowg * (long)ldc + col] = v;
      }
    }
  }
}

// ============ post_qkv: scores GEMM + V^T transpose, one launch ============
// blocks [0, ngemm)          : scores tile (bx=r&15, by=(r>>4)&15, z=r>>8)
// blocks [ngemm, ngemm+2048) : V^T 64x64 tiles
__global__ __launch_bounds__(256, 2)
void post_qkv(int ngemm,
              const u16* __restrict__ Qb, const u16* __restrict__ Kb,
              u16* __restrict__ Pd, u16* __restrict__ Pw,
              const u16* __restrict__ Vb, u16* __restrict__ vt) {
  __shared__ u16 smem[2 * 2 * 128 * 32];  // 32 KB
  int blk = blockIdx.x;
  int tid = threadIdx.x;
  if (blk < ngemm) {
    u16* sA0 = smem;
    u16* sB0 = smem + 2 * 128 * 32;
    int lane = tid & 63, wv = tid >> 6;
    int quad = lane >> 4, lm = lane & 15;
    int wr = wv >> 1, wc = wv & 1;
    int z = blk >> 8;
    long m0 = (long)(blk & 15) * 128, n0 = (long)((blk >> 4) & 15) * 128;
    const u16* A = Qb + (long)z * Sn * Dn;
    const u16* B = Kb + (long)z * Sn * Dn;
    u16* C = (z < 2) ? Pd + (long)z * Sn * Sn : Pw + (long)(z - 2) * Sn * Sn;

    f32x4 acc[4][4] = {};
    int srow = wv * 16 + (lane >> 2);
    int sch = (lane & 3) * 8;
    const u16* Ap = A + (m0 + srow) * 1024 + sch;
    const u16* Bp = B + (n0 + srow) * 1024 + sch;
    const int lofs = wv * 16 * 32;

    for (int k0 = 0; k0 < 1024; k0 += 64) {
      #pragma unroll
      for (int h = 0; h < 2; h++) {
        int kh = k0 + h * 32;
        gload_lds16(Ap + kh, &sA0[h * 128 * 32 + lofs]);
        gload_lds16(Ap + 64 * 1024 + kh, &sA0[h * 128 * 32 + lofs + 64 * 32]);
        gload_lds16(Bp + kh, &sB0[h * 128 * 32 + lofs]);
        gload_lds16(Bp + 64 * 1024 + kh, &sB0[h * 128 * 32 + lofs + 64 * 32]);
      }
      __syncthreads();
      #pragma unroll
      for (int h = 0; h < 2; h++) {
        bf16x8 af[4], bfr[4];
        #pragma unroll
        for (int mi = 0; mi < 4; mi++)
          af[mi] = *(const bf16x8*)&sA0[h * 128 * 32 + (wr * 64 + mi * 16 + lm) * 32 + quad * 8];
        #pragma unroll
        for (int ni = 0; ni < 4; ni++)
          bfr[ni] = *(const bf16x8*)&sB0[h * 128 * 32 + (wc * 64 + ni * 16 + lm) * 32 + quad * 8];
        #pragma unroll
        for (int mi = 0; mi < 4; mi++)
          #pragma unroll
          for (int ni = 0; ni < 4; ni++)
            acc[mi][ni] = __builtin_amdgcn_mfma_f32_16x16x32_bf16(af[mi], bfr[ni], acc[mi][ni], 0, 0, 0);
      }
      __syncthreads();
    }
    #pragma unroll
    for (int mi = 0; mi < 4; mi++) {
      #pragma unroll
      for (int ni = 0; ni < 4; ni++) {
        int col = (int)n0 + wc * 64 + ni * 16 + lm;
        #pragma unroll
        for (int r = 0; r < 4; r++) {
          long rowg = m0 + wr * 64 + mi * 16 + quad * 4 + r;
          C[rowg * 2048 + col] = f2bf(acc[mi][ni][r] * 0.03125f);
        }
      }
    }
  } else {
    u16 (*sm)[68] = (u16(*)[68])smem;
    int t = blk - ngemm;
    int b = t >> 9, r = t & 511;
    int j0 = (r & 15) << 6, i0 = ((r >> 4) & 31) << 6;
    const u16* s = Vb + (long)b * Sn * Dn;
    u16* d = vt + (long)b * Dn * Sn;
    int tx = tid & 15, r0 = tid >> 4;
    #pragma unroll
    for (int rr = r0; rr < 64; rr += 16) {
      ushort4 v = *(const ushort4*)&s[(long)(i0 + rr) * 1024 + j0 + tx * 4];
      sm[rr][tx*4+0] = v.x; sm[rr][tx*4+1] = v.y; sm[rr][tx*4+2] = v.z; sm[rr][tx*4+3] = v.w;
    }
    __syncthreads();
    #pragma unroll
    for (int cc = r0; cc < 64; cc += 16) {
      ushort4 o;
      o.x = sm[tx*4+0][cc]; o.y = sm[tx*4+1][cc];
      o.z = sm[tx*4+2][cc]; o.w = sm[tx*4+3][cc];
      *(ushort4*)&d[(long)(j0 + cc) * 2048 + i0 + tx * 4] = o;
    }
  }
}

// ============ smax_conv: softmax rows + grouped conv (V dead -> Vb free) ===
// blocks [0, nsm)           : softmax row (split pa/pb at rowsplit)
// blocks [nsm, nsm + nconv) : conv via MFMA, reads x & cw (f32) directly
__global__ __launch_bounds__(256)
void smax_conv(u16* __restrict__ pa, u16* __restrict__ pb, int rowsplit, int nsm,
               const float* __restrict__ x, const float* __restrict__ cw,
               const float* __restrict__ cb, u16* __restrict__ convo) {
  __shared__ u16 smem[22160];  // conv: sx 130x72 (9360 u16) + sw 64x200 (12800 u16)
  __shared__ float red[4];
  int blk = blockIdx.x;
  int tid = threadIdx.x;
  if (blk < nsm) {
    long row = blk;
    u16* p = (row < rowsplit) ? pa + row * 2048 : pb + (row - rowsplit) * 2048;
    ushort4 a = *(const ushort4*)&p[tid * 8];
    ushort4 b = *(const ushort4*)&p[tid * 8 + 4];
    float f0 = bf2f(a.x), f1 = bf2f(a.y), f2 = bf2f(a.z), f3 = bf2f(a.w);
    float f4 = bf2f(b.x), f5 = bf2f(b.y), f6 = bf2f(b.z), f7 = bf2f(b.w);
    float m = fmaxf(fmaxf(fmaxf(f0, f1), fmaxf(f2, f3)),
                    fmaxf(fmaxf(f4, f5), fmaxf(f6, f7)));
    m = block_allreduce_max(m, red, tid);
    float e0 = __expf(f0 - m), e1 = __expf(f1 - m), e2 = __expf(f2 - m), e3 = __expf(f3 - m);
    float e4 = __expf(f4 - m), e5 = __expf(f5 - m), e6 = __expf(f6 - m), e7 = __expf(f7 - m);
    float s = block_allreduce_sum(e0 + e1 + e2 + e3 + e4 + e5 + e6 + e7, red, tid);
    float inv = 1.0f / s;
    ushort4 o1, o2;
    o1.x = f2bf(e0 * inv); o1.y = f2bf(e1 * inv); o1.z = f2bf(e2 * inv); o1.w = f2bf(e3 * inv);
    o2.x = f2bf(e4 * inv); o2.y = f2bf(e5 * inv); o2.z = f2bf(e6 * inv); o2.w = f2bf(e7 * inv);
    *(ushort4*)&p[tid * 8] = o1;
    *(ushort4*)&p[tid * 8 + 4] = o2;
  } else {
    // conv: out[s,oc] = cb[oc] + sum_k x[s+t-1, g*64+i]*w[oc, k=t*64+i]
    u16 (*sx)[72] = (u16(*)[72])smem;
    u16 (*sw)[200] = (u16(*)[200])(smem + 9360);
    int r = blk - nsm;
    int s0 = (r & 15) * 128;
    int g = (r >> 4) & 15;
    int b = r >> 8;
    int lane = tid & 63, wv = tid >> 6;
    int quad = lane >> 4, lm = lane & 15;
    for (int idx = tid; idx < 64 * 192; idx += 256) {
      int oc = idx / 192, k = idx - oc * 192;
      int t = k >> 6, i = k & 63;
      sw[oc][k] = f2bf(cw[((long)(g * 64 + oc)) * 192 + i * 3 + t]);
    }
    for (int idx = tid; idx < 130 * 16; idx += 256) {
      int rr = idx >> 4, c4 = (idx & 15) * 4;
      int s = s0 - 1 + rr;
      ushort4 v;
      if (s >= 0 && s < Sn) {
        float4 f = *(const float4*)&x[((long)b * Sn + s) * Dn + g * 64 + c4];
        v.x = f2bf(f.x); v.y = f2bf(f.y); v.z = f2bf(f.z); v.w = f2bf(f.w);
      } else { v.x = 0; v.y = 0; v.z = 0; v.w = 0; }
      *(ushort4*)&sx[rr][c4] = v;
    }
    __syncthreads();
    f32x4 acc[2][4] = {};
    #pragma unroll
    for (int ks = 0; ks < 6; ks++) {
      int t = ks >> 1;
      int i0 = (ks & 1) * 32 + quad * 8;
      bf16x8 a0 = *(const bf16x8*)&sx[wv * 32 + lm + t][i0];
      bf16x8 a1 = *(const bf16x8*)&sx[wv * 32 + 16 + lm + t][i0];
      #pragma unroll
      for (int nf = 0; nf < 4; nf++) {
        bf16x8 bf = *(const bf16x8*)&sw[nf * 16 + lm][ks * 32 + quad * 8];
        acc[0][nf] = __builtin_amdgcn_mfma_f32_16x16x32_bf16(a0, bf, acc[0][nf], 0, 0, 0);
        acc[1][nf] = __builtin_amdgcn_mfma_f32_16x16x32_bf16(a1, bf, acc[1][nf], 0, 0, 0);
      }
    }
    #pragma unroll
    for (int mi = 0; mi < 2; mi++) {
      #pragma unroll
      for (int nf = 0; nf < 4; nf++) {
        int col = g * 64 + nf * 16 + lm;
        float bias = cb[col];
        #pragma unroll
        for (int rr = 0; rr < 4; rr++) {
          int row = wv * 32 + mi * 16 + quad * 4 + rr;
          convo[((long)b * Sn + s0 + row) * Dn + col] = f2bf(acc[mi][nf][rr] + bias);
        }
      }
    }
  }
}

// ============ pv_ln: PV GEMM (flattened) + LN(conv) in place ===============
// blocks [0, npv)         : PV tile (bx=r&15, by=(r>>4)&7, z=r>>7); K=2048
// blocks [npv, npv+8192)  : LN(conv) row, in place
__global__ __launch_bounds__(256, 2)
void pv_ln(int npv,
           const u16* __restrict__ Pd, const u16* __restrict__ Pw,
           const u16* __restrict__ vt, u16* __restrict__ attn,
           u16* __restrict__ conv,
           const float* __restrict__ gamma, const float* __restrict__ beta) {
  __shared__ u16 smem[2 * 2 * 128 * 32];  // 32 KB
  __shared__ float red[4];
  int blk = blockIdx.x;
  int tid = threadIdx.x;
  if (blk < npv) {
    u16* sA0 = smem;
    u16* sB0 = smem + 2 * 128 * 32;
    int lane = tid & 63, wv = tid >> 6;
    int quad = lane >> 4, lm = lane & 15;
    int wr = wv >> 1, wc = wv & 1;
    int z = blk >> 7;
    long m0 = (long)(blk & 15) * 128, n0 = (long)((blk >> 4) & 7) * 128;
    const u16* A = (z < 2) ? Pd + (long)z * Sn * Sn : Pw + (long)(z - 2) * Sn * Sn;
    const u16* B = vt + (long)z * Dn * Sn;
    u16* C = attn + (long)z * Sn * Dn;

    f32x4 acc[4][4] = {};
    int srow = wv * 16 + (lane >> 2);
    int sch = (lane & 3) * 8;
    const u16* Ap = A + (m0 + srow) * 2048 + sch;
    const u16* Bp = B + (n0 + srow) * 2048 + sch;
    const int lofs = wv * 16 * 32;

    for (int k0 = 0; k0 < 2048; k0 += 64) {
      #pragma unroll
      for (int h = 0; h < 2; h++) {
        int kh = k0 + h * 32;
        gload_lds16(Ap + kh, &sA0[h * 128 * 32 + lofs]);
        gload_lds16(Ap + 64 * 2048 + kh, &sA0[h * 128 * 32 + lofs + 64 * 32]);
        gload_lds16(Bp + kh, &sB0[h * 128 * 32 + lofs]);
        gload_lds16(Bp + 64 * 2048 + kh, &sB0[h * 128 * 32 + lofs + 64 * 32]);
      }
      __syncthreads();
      #pragma unroll
      for (int h = 0; h < 2; h++) {
        bf16x8 af[4], bfr[4];
        #pragma unroll
        for (int mi = 0; mi < 4; mi++)
          af[mi] = *(const bf16x8*)&sA0[h * 128 * 32 + (wr * 64 + mi * 16 + lm) * 32 + quad * 8];
        #pragma unroll
        for (int ni = 0; ni < 4; ni++)
          bfr[ni] = *(const bf16x8*)&sB0[h * 128 * 32 + (wc * 64 + ni * 16 + lm) * 32 + quad * 8];
        #pragma unroll
        for (int mi = 0; mi < 4; mi++)
          #pragma unroll
          for (int ni = 0; ni < 4; ni++)
            acc[mi][ni] = __builtin_amdgcn_mfma_f32_16x16x32_bf16(af[mi], bfr[ni], acc[mi][ni], 0, 0, 0);
      }
      __syncthreads();
    }
    #pragma unroll
    for (int mi = 0; mi < 4; mi++) {
      #pragma unroll
      for (int ni = 0; ni < 4; ni++) {
        int col = (int)n0 + wc * 64 + ni * 16 + lm;
        #pragma unroll
        for (int r = 0; r < 4; r++) {
          long rowg = m0 + wr * 64 + mi * 16 + quad * 4 + r;
          C[rowg * 1024 + col] = f2bf(acc[mi][ni][r]);
        }
      }
    }
  } else {
    long row = blk - npv;
    ln_row(conv, nullptr, gamma, beta, conv, row, tid, red);
  }
}

// ================= layernorm standalone =================
__global__ __launch_bounds__(256)
void ln_kernel(const u16* __restrict__ a, const u16* __restrict__ b2,
               const float* __restrict__ gamma, const float* __restrict__ beta,
               u16* __restrict__ out) {
  __shared__ float red[4];
  ln_row(a, b2, gamma, beta, out, blockIdx.x, threadIdx.x, red);
}

// ================= workspace layout =================
static const size_t OFF_WT    = 0;
static const size_t OFF_QKVB  = 8ull << 20;
static const size_t OFF_Q     = 9ull << 20;
static const size_t OFF_K     = 25ull << 20;
static const size_t OFF_V     = 41ull << 20;
static const size_t OFF_PW    = 57ull << 20;

extern "C" void kernel_launch(void* const* d_in, const int* in_sizes, int n_in,
                              void* d_out, int out_size, void* d_ws, size_t ws_size,
                              hipStream_t stream) {
  const float* x     = (const float*)d_in[0];
  const float* Wq    = (const float*)d_in[1];
  const float* bq    = (const float*)d_in[2];
  const float* Wk    = (const float*)d_in[3];
  const float* Wv    = (const float*)d_in[4];
  const float* bv    = (const float*)d_in[5];
  const float* cw    = (const float*)d_in[6];
  const float* cb    = (const float*)d_in[7];
  const float* gamma = (const float*)d_in[8];
  const float* beta  = (const float*)d_in[9];
  const float* Wo    = (const float*)d_in[10];
  const float* bo    = (const float*)d_in[11];
  float* out = (float*)d_out;
  char* ws = (char*)d_ws;

  u16*   wT    = (u16*)(ws + OFF_WT);
  float* qkvb  = (float*)(ws + OFF_QKVB);
  u16*   Qb    = (u16*)(ws + OFF_Q);
  u16*   Kb    = (u16*)(ws + OFF_K);
  u16*   Vb    = (u16*)(ws + OFF_V);
  u16*   Pw    = (u16*)(ws + OFF_PW);
  u16*   xb    = (u16*)d_out;               // dead after QKV; then P b0,1
  u16*   Pd    = (u16*)d_out;
  u16*   vt    = (u16*)d_out + 8388608;     // V^T, dead after PV
  u16*   conv  = Vb;                        // written only after V^T done
  u16*   attn  = Qb;
  u16*   combined = Kb;
  const long PBS = (long)Sn * Sn;

  dim3 tb(256);

  // 1. prologue: weights T + bias + x cvt
  prep_all<<<dim3(9217), tb, 0, stream>>>(Wq, Wk, Wv, Wo, wT, bq, bv, qkvb, x, xb);
  // 2. QKV (z = Q,K,V planes)
  gemm_nt<u16><<<dim3(64, 8, 3), tb, 0, stream>>>(
      xb, nullptr, 0, 1024, wT, 1048576, 1024, Qb, (u16*)nullptr, 8388608, 1024,
      99, 1024, 1.0f, qkvb, 1024, nullptr, 0, 0);

  if (ws_size >= (73ull << 20)) {
    // 3. scores GEMM + V^T (V consumed here; Vb free afterwards)
    post_qkv<<<dim3(1024 + 2048), tb, 0, stream>>>(1024, Qb, Kb, Pd, Pw, Vb, vt);
    // 4. softmax (8192 rows) + conv (1024 blocks) -> conv into Vb
    smax_conv<<<dim3(8192 + 1024), tb, 0, stream>>>(Pd, Pw, 4096, 8192,
                                                    x, cw, cb, conv);
    // 5. PV (512 tiles) + LN(conv) in place (8192 rows)
    pv_ln<<<dim3(512 + 8192), tb, 0, stream>>>(512, Pd, Pw, vt, attn, conv,
                                               gamma, beta);
  } else {
    // fallback: V^T only, then chunked attention; conv rides chunk-0 softmax
    post_qkv<<<dim3(2048), tb, 0, stream>>>(0, Qb, Kb, Pd, Pw, Vb, vt);
    for (int c = 0; c < 2; c++) {
      long off = (long)c * 2 * Sn * Dn;
      gemm_nt<u16><<<dim3(16, 16, 2), tb, 0, stream>>>(
          Qb + off, nullptr, (long)Sn * Dn, 1024, Kb + off, (long)Sn * Dn, 1024,
          Pd, (u16*)nullptr, PBS, 2048,
          99, 1024, 0.03125f, nullptr, 0, nullptr, 0, 0);
      smax_conv<<<dim3(4096 + (c == 0 ? 1024 : 0)), tb, 0, stream>>>(
          Pd, Pd, 4096, 4096, x, cw, cb, conv);
      gemm_nt<u16><<<dim3(16, 8, 2), tb, 0, stream>>>(
          Pd, nullptr, PBS, 2048, vt + off, (long)Dn * Sn, 2048,
          attn + off, (u16*)nullptr, (long)Sn * Dn, 1024,
          99, 2048, 1.0f, nullptr, 0, nullptr, 0, 0);
    }
    ln_kernel<<<dim3(8192), tb, 0, stream>>>(conv, nullptr, gamma, beta, conv);
  }

  // 6. combined = LN(conv + attn); 7. out = combined @ Wo + bo + x
  ln_kernel<<<dim3(8192), tb, 0, stream>>>(conv, attn, gamma, beta, combined);
  gemm_nt<float><<<dim3(64, 8, 1), tb, 0, stream>>>(
      combined, nullptr, 0, 1024, wT + 3u * 1048576u, 0, 1024,
      out, (float*)nullptr, 0, 1024,
      99, 1024, 1.0f, bo, 0, x, 0, 1024);
}